// Round 1
// baseline (2140.182 us; speedup 1.0000x reference)
//
#include <hip/hip_runtime.h>

#define NHEAD 96
#define SEQ   2048
#define DD    128

// One wave (64 threads) per (head, 16-column slice of DV).
// lane = kg*16 + cl ; kg in [0,4) owns k-rows [kg*32, kg*32+32); col = cb*16+cl.
// Each thread keeps st[j] = state[kg*32+j][col] in registers.
__global__ __launch_bounds__(64)
void gdn_seq_kernel(const float* __restrict__ Q, const float* __restrict__ K,
                    const float* __restrict__ V, const float* __restrict__ G,
                    const float* __restrict__ BETA,
                    float* __restrict__ Out, float* __restrict__ FS) {
  __shared__ __align__(16) float kbuf[DD];
  __shared__ __align__(16) float qbuf[DD];

  const int lane = threadIdx.x;
  const int head = blockIdx.x >> 3;
  const int cb   = blockIdx.x & 7;
  const int kg   = lane >> 4;
  const int cl   = lane & 15;
  const int col  = cb * 16 + cl;

  const size_t rb = (size_t)head * SEQ * DD;
  const float* qp = Q + rb;
  const float* kp = K + rb;
  const float* vp = V + rb;
  const float* gp = G + (size_t)head * SEQ;
  const float* bp = BETA + (size_t)head * SEQ;
  float* op  = Out + rb;
  float* fsp = FS + (size_t)head * DD * DD;

  float st[32];
  #pragma unroll
  for (int j = 0; j < 32; ++j) st[j] = 0.f;

  const float qscale = 0.08838834764831845f;  // 1/sqrt(128)

  // ---- prologue: load+normalize t=0; raw-load t=1 ----
  float ckn0, ckn1, cqn0, cqn1, cv, ceg, cbt;
  {
    float k0 = kp[lane], k1 = kp[64 + lane];
    float q0 = qp[lane], q1 = qp[64 + lane];
    cv = vp[col];
    float gg = gp[0]; cbt = bp[0];
    float ssk = fmaf(k0, k0, k1 * k1);
    float ssq = fmaf(q0, q0, q1 * q1);
    #pragma unroll
    for (int d = 1; d < 64; d <<= 1) {
      ssk += __shfl_xor(ssk, d);
      ssq += __shfl_xor(ssq, d);
    }
    float ik = 1.f / fmaxf(sqrtf(ssk), 1e-6f);
    float iq = qscale / fmaxf(sqrtf(ssq), 1e-6f);
    ckn0 = k0 * ik; ckn1 = k1 * ik;
    cqn0 = q0 * iq; cqn1 = q1 * iq;
    ceg = __expf(gg);
  }
  float nk0, nk1, nq0, nq1, nv, ng, nb;
  {
    const float* krow = kp + DD;
    const float* qrow = qp + DD;
    nk0 = krow[lane]; nk1 = krow[64 + lane];
    nq0 = qrow[lane]; nq1 = qrow[64 + lane];
    nv = vp[DD + col]; ng = gp[1]; nb = bp[1];
  }

  for (int t = 0; t < SEQ; ++t) {
    // stage current normalized k/q into LDS (wave-private block; no __syncthreads:
    // same-wave DS FIFO ordering + compiler fences keep this correct, and avoids
    // the vmcnt(0) drain a barrier would force on our prefetch).
    __builtin_amdgcn_wave_barrier();
    kbuf[lane] = ckn0; kbuf[64 + lane] = ckn1;
    qbuf[lane] = cqn0; qbuf[64 + lane] = cqn1;
    __builtin_amdgcn_wave_barrier();

    // software prefetch t+2 (clamped)
    int t2 = t + 2; if (t2 > SEQ - 1) t2 = SEQ - 1;
    const float* krow = kp + (size_t)t2 * DD;
    const float* qrow = qp + (size_t)t2 * DD;
    float pk0 = krow[lane], pk1 = krow[64 + lane];
    float pq0 = qrow[lane], pq1 = qrow[64 + lane];
    float pv = vp[(size_t)t2 * DD + col];
    float pg = gp[t2], pb = bp[t2];

    // start norm reduction for t+1 (latency hides under FMA passes below)
    float ssk = fmaf(nk0, nk0, nk1 * nk1);
    float ssq = fmaf(nq0, nq0, nq1 * nq1);
    #pragma unroll
    for (int d = 1; d < 64; d <<= 1) {
      ssk += __shfl_xor(ssk, d);
      ssq += __shfl_xor(ssq, d);
    }

    // ---- pass A: state decay + kv = k^T state ----
    float kv0 = 0.f, kv1 = 0.f, kv2 = 0.f, kv3 = 0.f;
    #pragma unroll
    for (int j = 0; j < 32; j += 4) {
      const float4 kn = *(const float4*)&kbuf[kg * 32 + j];
      st[j]     *= ceg; st[j + 1] *= ceg; st[j + 2] *= ceg; st[j + 3] *= ceg;
      kv0 = fmaf(kn.x, st[j],     kv0);
      kv1 = fmaf(kn.y, st[j + 1], kv1);
      kv2 = fmaf(kn.z, st[j + 2], kv2);
      kv3 = fmaf(kn.w, st[j + 3], kv3);
    }
    float kv = (kv0 + kv1) + (kv2 + kv3);
    kv += __shfl_xor(kv, 16);
    kv += __shfl_xor(kv, 32);
    const float dl = (cv - kv) * cbt;

    // ---- pass B/C: rank-1 update + out = q^T state ----
    float os0 = 0.f, os1 = 0.f, os2 = 0.f, os3 = 0.f;
    #pragma unroll
    for (int j = 0; j < 32; j += 4) {
      const float4 kn = *(const float4*)&kbuf[kg * 32 + j];
      const float4 qn = *(const float4*)&qbuf[kg * 32 + j];
      st[j]     = fmaf(kn.x, dl, st[j]);
      st[j + 1] = fmaf(kn.y, dl, st[j + 1]);
      st[j + 2] = fmaf(kn.z, dl, st[j + 2]);
      st[j + 3] = fmaf(kn.w, dl, st[j + 3]);
      os0 = fmaf(qn.x, st[j],     os0);
      os1 = fmaf(qn.y, st[j + 1], os1);
      os2 = fmaf(qn.z, st[j + 2], os2);
      os3 = fmaf(qn.w, st[j + 3], os3);
    }
    float os = (os0 + os1) + (os2 + os3);
    os += __shfl_xor(os, 16);
    os += __shfl_xor(os, 32);
    if (kg == 0) op[(size_t)t * DD + col] = os;
    __builtin_amdgcn_wave_barrier();

    // finish t+1 normalization -> cur ; rotate prefetch -> nxt
    float ik = 1.f / fmaxf(sqrtf(ssk), 1e-6f);
    float iq = qscale / fmaxf(sqrtf(ssq), 1e-6f);
    ckn0 = nk0 * ik; ckn1 = nk1 * ik;
    cqn0 = nq0 * iq; cqn1 = nq1 * iq;
    ceg = __expf(ng);
    cv = nv; cbt = nb;
    nk0 = pk0; nk1 = pk1; nq0 = pq0; nq1 = pq1;
    nv = pv; ng = pg; nb = pb;
  }

  // ---- final state write ----
  #pragma unroll
  for (int j = 0; j < 32; ++j) {
    fsp[(size_t)(kg * 32 + j) * DD + col] = st[j];
  }
}

extern "C" void kernel_launch(void* const* d_in, const int* in_sizes, int n_in,
                              void* d_out, int out_size, void* d_ws, size_t ws_size,
                              hipStream_t stream) {
  const float* Q    = (const float*)d_in[0];
  const float* K    = (const float*)d_in[1];
  const float* V    = (const float*)d_in[2];
  const float* G    = (const float*)d_in[3];
  const float* BETA = (const float*)d_in[4];
  float* Out = (float*)d_out;
  float* FS  = Out + (size_t)NHEAD * SEQ * DD;

  dim3 grid(NHEAD * 8), block(64);
  hipLaunchKernelGGL(gdn_seq_kernel, grid, block, 0, stream,
                     Q, K, V, G, BETA, Out, FS);
}

// Round 2
// 357.826 us; speedup vs baseline: 5.9811x; 5.9811x over previous
//
#include <hip/hip_runtime.h>

typedef __attribute__((ext_vector_type(8))) short short8;
typedef __attribute__((ext_vector_type(4))) float f32x4;
typedef __attribute__((ext_vector_type(4))) unsigned short ushort4v;

#define NH   96
#define SEQL 2048
#define DD   128
#define CC   64
#define NCH  32
#define SK   136   // padded stride (ushorts) for 128-col bf16 mats
#define S64  72    // padded stride for 64-col bf16 mats

// arena offsets (ushort units) — Neumann phase
#define AX0  0
#define AX0T 4608
#define AX1  9216
#define AX1T 13824
#define APA  18432
#define APB  23040
// post-T aliases (X/P slots dead by then; P5 in APB untouched)
#define AW   0
#define AM   8704
#define ADT  13312
#define ADST 17920

__device__ __forceinline__ unsigned short f2bf(float f){
  union { float f; unsigned u; } v; v.f = f;
  unsigned r = v.u + 0x7FFFu + ((v.u >> 16) & 1u);
  return (unsigned short)(r >> 16);
}
__device__ __forceinline__ float bf2f(unsigned short u){
  union { unsigned u; float f; } v; v.u = ((unsigned)u) << 16; return v.f;
}
// A-frag (row-major mat) or B-frag (from transposed copy): lane holds 8
// contiguous bf16 at [row0 + (l&15)][kt*32 + (l>>4)*8 ...]
__device__ __forceinline__ short8 frag8(const unsigned short* b, int stride, int row0, int kt, int lane){
  return *(const short8*)&b[(row0 + (lane & 15)) * stride + kt * 32 + ((lane >> 4) << 3)];
}
#define MFMA16(a,b,c) __builtin_amdgcn_mfma_f32_16x16x32_bf16(a,b,c,0,0,0)
// raw barrier: drain LDS only (keeps global register-prefetch in flight)
#define BAR() do { asm volatile("s_waitcnt lgkmcnt(0)" ::: "memory"); __builtin_amdgcn_s_barrier(); } while(0)

__global__ __launch_bounds__(512, 1)
void gdn_chunk_kernel(const float* __restrict__ Qg, const float* __restrict__ Kg,
                      const float* __restrict__ Vg, const float* __restrict__ Gg,
                      const float* __restrict__ Bg,
                      float* __restrict__ Out, float* __restrict__ FS)
{
  __shared__ __align__(16) unsigned short sKc[64*SK];   // normalized k   [tok][d]
  __shared__ __align__(16) unsigned short sQc[64*SK];   // w_t-scaled q~  [tok][d]
  __shared__ __align__(16) unsigned short sS0T[64*SK];  // state^T bf16   [v][d]
  __shared__ __align__(16) unsigned short sKT[DD*S64];  // k^T            [d][tok]
  __shared__ __align__(16) unsigned short sT2[64*S64];  // -T*diag(beta*w)
  __shared__ __align__(16) unsigned short sT3[64*S64];  //  T*diag(beta)
  __shared__ __align__(16) unsigned short sVT[64*S64];  // V-half^T       [v][tok]
  __shared__ __align__(16) unsigned short sAr[6*64*S64];
  __shared__ float sgs[64];
  __shared__ float sbe[64];

  const int tid  = threadIdx.x;
  const int w    = tid >> 6;
  const int lane = tid & 63;
  const int head = blockIdx.x % NH;   // pair (head, head+96*vh): same XCD (96%8==0)
  const int vh   = blockIdx.x / NH;

  const size_t rb = (size_t)head * SEQL * DD;
  const float* qp = Qg + rb;
  const float* kp = Kg + rb;
  const float* vp = Vg + rb + vh * 64;
  const float* gp = Gg + (size_t)head * SEQL;
  const float* bp = Bg + (size_t)head * SEQL;
  float* op  = Out + rb + vh * 64;
  float* fsp = FS + (size_t)head * DD * DD + vh * 64;

  const int lrow = tid >> 3;          // token row this thread loads (0..63)
  const int c16  = (tid & 7) * 16;    // k/q col base
  const int c8   = (tid & 7) * 8;     // v col base

  // state: wave w owns k-rows [16w,16w+16), 4 col-tiles of 16 (f32x4 each, D-layout)
  f32x4 s[4];
  #pragma unroll
  for (int i = 0; i < 4; ++i) s[i] = (f32x4){0.f,0.f,0.f,0.f};

  f32x4 kr[4], qr[4], vr[2]; float gr = 0.f, br = 0.f;

  auto prefetch = [&](int t0p){
    const float* kb = kp + (size_t)(t0p + lrow) * DD + c16;
    const float* qb = qp + (size_t)(t0p + lrow) * DD + c16;
    const float* vb = vp + (size_t)(t0p + lrow) * DD + c8;
    #pragma unroll
    for (int i = 0; i < 4; ++i) { kr[i] = *(const f32x4*)(kb + 4*i); qr[i] = *(const f32x4*)(qb + 4*i); }
    #pragma unroll
    for (int i = 0; i < 2; ++i) vr[i] = *(const f32x4*)(vb + 4*i);
    if (w == 0) { gr = gp[t0p + lane]; br = bp[t0p + lane]; }
  };

  prefetch(0);

  for (int tc = 0; tc < NCH; ++tc) {
    const int t0 = tc * CC;

    // ---- ph0: write S0^T (bf16) from state regs; wave0: g-scan ----
    {
      const int m0 = 16*w + ((lane >> 4) << 2);
      const int nl = lane & 15;
      #pragma unroll
      for (int nt = 0; nt < 4; ++nt) {
        ushort4v p;
        #pragma unroll
        for (int r = 0; r < 4; ++r) p[r] = f2bf(s[nt][r]);
        *(ushort4v*)&sS0T[(nt*16 + nl) * SK + m0] = p;
      }
    }
    if (w == 0) {
      float sc = gr;
      #pragma unroll
      for (int d = 1; d < 64; d <<= 1) { float t = __shfl_up(sc, d); if (lane >= d) sc += t; }
      sgs[lane] = sc; sbe[lane] = br;
    }
    BAR();

    // ---- ph1: normalize & stage K,Q,V; issue next-chunk prefetch ----
    {
      float ssk = 0.f, ssq = 0.f;
      #pragma unroll
      for (int i = 0; i < 4; ++i) {
        ssk += kr[i][0]*kr[i][0] + kr[i][1]*kr[i][1] + kr[i][2]*kr[i][2] + kr[i][3]*kr[i][3];
        ssq += qr[i][0]*qr[i][0] + qr[i][1]*qr[i][1] + qr[i][2]*qr[i][2] + qr[i][3]*qr[i][3];
      }
      ssk += __shfl_xor(ssk, 1); ssk += __shfl_xor(ssk, 2); ssk += __shfl_xor(ssk, 4);
      ssq += __shfl_xor(ssq, 1); ssq += __shfl_xor(ssq, 2); ssq += __shfl_xor(ssq, 4);
      const float ik = 1.f / fmaxf(sqrtf(ssk), 1e-6f);
      const float iq = 0.08838834764831845f / fmaxf(sqrtf(ssq), 1e-6f) * __expf(sgs[lrow]);
      #pragma unroll
      for (int i = 0; i < 4; ++i) {
        ushort4v pk, pq;
        #pragma unroll
        for (int r = 0; r < 4; ++r) { pk[r] = f2bf(kr[i][r] * ik); pq[r] = f2bf(qr[i][r] * iq); }
        *(ushort4v*)&sKc[lrow*SK + c16 + 4*i] = pk;
        *(ushort4v*)&sQc[lrow*SK + c16 + 4*i] = pq;
        #pragma unroll
        for (int r = 0; r < 4; ++r) sKT[(c16 + 4*i + r)*S64 + lrow] = pk[r];
      }
      #pragma unroll
      for (int i = 0; i < 2; ++i) {
        #pragma unroll
        for (int r = 0; r < 4; ++r) sVT[(c8 + 4*i + r)*S64 + lrow] = f2bf(vr[i][r]);
      }
    }
    prefetch(tc < NCH-1 ? (tc+1)*CC : t0);
    BAR();

    // ---- ph2: KK^T -> A (masked+scaled), A^T, P0 = I - A ----
    #pragma unroll
    for (int j = 0; j < 2; ++j) {
      const int tI = 2*w + j, mt = tI >> 2, nt = tI & 3;
      f32x4 acc = (f32x4){0.f,0.f,0.f,0.f};
      #pragma unroll
      for (int kt = 0; kt < 4; ++kt)
        acc = MFMA16(frag8(sKc, SK, mt*16, kt, lane), frag8(sKc, SK, nt*16, kt, lane), acc);
      const int n  = nt*16 + (lane & 15);
      const int m0 = mt*16 + ((lane >> 4) << 2);
      ushort4v pt;
      #pragma unroll
      for (int r = 0; r < 4; ++r) {
        const int m = m0 + r;
        const float a = (m > n) ? sbe[m] * __expf(sgs[m] - sgs[n]) * acc[r] : 0.f;
        const unsigned short ab = f2bf(a);
        sAr[AX0 + m*S64 + n] = ab;
        pt[r] = ab;
        sAr[APA + m*S64 + n] = f2bf((m == n ? 1.f : 0.f) - a);
      }
      *(ushort4v*)&sAr[AX0T + n*S64 + m0] = pt;
    }
    BAR();

    // ---- ph3..ph8: T = (I-A)(I+A^2)(I+A^4)(I+A^8)(I+A^16)(I+A^32) ----
    #pragma unroll
    for (int lev = 0; lev < 6; ++lev) {
      const int xs  = (lev & 1) ? AX1  : AX0;
      const int xsT = (lev & 1) ? AX1T : AX0T;
      const int xd  = (lev & 1) ? AX0  : AX1;
      const int xdT = (lev & 1) ? AX0T : AX1T;
      const int pa  = (lev & 1) ? APA  : APB;
      const int pd  = (lev & 1) ? APB  : APA;
      if (lev < 5) {  // squaring: Xnew = X*X
        #pragma unroll
        for (int j = 0; j < 2; ++j) {
          const int tI = 2*w + j, mt = tI >> 2, nt = tI & 3;
          f32x4 acc = (f32x4){0.f,0.f,0.f,0.f};
          #pragma unroll
          for (int kt = 0; kt < 2; ++kt)
            acc = MFMA16(frag8(sAr + xs, S64, mt*16, kt, lane), frag8(sAr + xsT, S64, nt*16, kt, lane), acc);
          const int n = nt*16 + (lane & 15), m0 = mt*16 + ((lane >> 4) << 2);
          ushort4v pt;
          #pragma unroll
          for (int r = 0; r < 4; ++r) { const unsigned short b = f2bf(acc[r]); sAr[xd + (m0+r)*S64 + n] = b; pt[r] = b; }
          *(ushort4v*)&sAr[xdT + n*S64 + m0] = pt;
        }
      }
      if (lev > 0) {  // product: Pnew = P + P*X
        #pragma unroll
        for (int j = 0; j < 2; ++j) {
          const int tI = 2*w + j, mt = tI >> 2, nt = tI & 3;
          const int n = nt*16 + (lane & 15), m0 = mt*16 + ((lane >> 4) << 2);
          f32x4 acc;
          #pragma unroll
          for (int r = 0; r < 4; ++r) acc[r] = bf2f(sAr[pa + (m0+r)*S64 + n]);
          #pragma unroll
          for (int kt = 0; kt < 2; ++kt)
            acc = MFMA16(frag8(sAr + pa, S64, mt*16, kt, lane), frag8(sAr + xsT, S64, nt*16, kt, lane), acc);
          #pragma unroll
          for (int r = 0; r < 4; ++r) sAr[pd + (m0+r)*S64 + n] = f2bf(acc[r]);
        }
      }
      BAR();
    }
    // T = P5 sits in APB

    // ---- ph9: T2 = -T*diag(beta*w), T3 = T*diag(beta) ----
    {
      const int i = tid >> 3, j0 = (tid & 7) * 8;
      #pragma unroll
      for (int j = 0; j < 8; ++j) {
        const float t = bf2f(sAr[APB + i*S64 + j0 + j]);
        const float bj = sbe[j0 + j];
        const float wj = __expf(sgs[j0 + j]);
        sT2[i*S64 + j0 + j] = f2bf(-t * bj * wj);
        sT3[i*S64 + j0 + j] = f2bf(t * bj);
      }
    }
    BAR();

    // ---- ph10: U = T3*V (regs); M = tril(QK)*e^{-gs_i}; W = T2*K ----
    f32x4 uacc[2];
    #pragma unroll
    for (int j = 0; j < 2; ++j) {
      const int tI = 2*w + j, mt = tI >> 2, nt = tI & 3;
      f32x4 acc = (f32x4){0.f,0.f,0.f,0.f};
      #pragma unroll
      for (int kt = 0; kt < 2; ++kt)
        acc = MFMA16(frag8(sT3, S64, mt*16, kt, lane), frag8(sVT, S64, nt*16, kt, lane), acc);
      uacc[j] = acc;
    }
    #pragma unroll
    for (int j = 0; j < 2; ++j) {
      const int tI = 2*w + j, mt = tI >> 2, nt = tI & 3;
      f32x4 acc = (f32x4){0.f,0.f,0.f,0.f};
      #pragma unroll
      for (int kt = 0; kt < 4; ++kt)
        acc = MFMA16(frag8(sQc, SK, mt*16, kt, lane), frag8(sKc, SK, nt*16, kt, lane), acc);
      const int n = nt*16 + (lane & 15), m0 = mt*16 + ((lane >> 4) << 2);
      const float en = __expf(-sgs[n]);
      #pragma unroll
      for (int r = 0; r < 4; ++r) {
        const int m = m0 + r;
        sAr[AM + m*S64 + n] = f2bf((n <= m) ? acc[r] * en : 0.f);
      }
    }
    #pragma unroll
    for (int j = 0; j < 4; ++j) {
      const int mt = w >> 1, nt = (w & 1) * 4 + j;
      f32x4 acc = (f32x4){0.f,0.f,0.f,0.f};
      #pragma unroll
      for (int kt = 0; kt < 2; ++kt)
        acc = MFMA16(frag8(sT2, S64, mt*16, kt, lane), frag8(sKT, S64, nt*16, kt, lane), acc);
      const int n = nt*16 + (lane & 15), m0 = mt*16 + ((lane >> 4) << 2);
      #pragma unroll
      for (int r = 0; r < 4; ++r) sAr[AW + (m0+r)*SK + n] = f2bf(acc[r]);
    }
    BAR();

    // ---- ph11: delta = U + W*S0 -> dT,dsT; outS = Q~*S0 (regs); decay S ----
    f32x4 oacc[2];
    {
      const float g63 = sgs[63];
      #pragma unroll
      for (int j = 0; j < 2; ++j) {
        const int tI = 2*w + j, mt = tI >> 2, nt = tI & 3;
        f32x4 acc = uacc[j];
        #pragma unroll
        for (int kt = 0; kt < 4; ++kt)
          acc = MFMA16(frag8(sAr + AW, SK, mt*16, kt, lane), frag8(sS0T, SK, nt*16, kt, lane), acc);
        const int n = nt*16 + (lane & 15), m0 = mt*16 + ((lane >> 4) << 2);
        ushort4v pt, ps;
        #pragma unroll
        for (int r = 0; r < 4; ++r) {
          pt[r] = f2bf(acc[r]);
          ps[r] = f2bf(acc[r] * __expf(g63 - sgs[m0 + r]));
        }
        *(ushort4v*)&sAr[ADT  + n*S64 + m0] = pt;
        *(ushort4v*)&sAr[ADST + n*S64 + m0] = ps;
      }
      #pragma unroll
      for (int j = 0; j < 2; ++j) {
        const int tI = 2*w + j, mt = tI >> 2, nt = tI & 3;
        f32x4 acc = (f32x4){0.f,0.f,0.f,0.f};
        #pragma unroll
        for (int kt = 0; kt < 4; ++kt)
          acc = MFMA16(frag8(sQc, SK, mt*16, kt, lane), frag8(sS0T, SK, nt*16, kt, lane), acc);
        oacc[j] = acc;
      }
      const float w63 = __expf(g63);
      #pragma unroll
      for (int nt = 0; nt < 4; ++nt) s[nt] = s[nt] * w63;
    }
    BAR();

    // ---- ph12: out = outS + M*delta -> global; S += K^T * delta_scaled ----
    #pragma unroll
    for (int j = 0; j < 2; ++j) {
      const int tI = 2*w + j, mt = tI >> 2, nt = tI & 3;
      f32x4 acc = oacc[j];
      #pragma unroll
      for (int kt = 0; kt < 2; ++kt)
        acc = MFMA16(frag8(sAr + AM, S64, mt*16, kt, lane), frag8(sAr + ADT, S64, nt*16, kt, lane), acc);
      const int n = nt*16 + (lane & 15), m0 = mt*16 + ((lane >> 4) << 2);
      #pragma unroll
      for (int r = 0; r < 4; ++r)
        op[(size_t)(t0 + m0 + r) * DD + n] = acc[r];
    }
    #pragma unroll
    for (int nt = 0; nt < 4; ++nt) {
      f32x4 acc = s[nt];
      #pragma unroll
      for (int kt = 0; kt < 2; ++kt)
        acc = MFMA16(frag8(sKT, S64, w*16, kt, lane), frag8(sAr + ADST, S64, nt*16, kt, lane), acc);
      s[nt] = acc;
    }
    BAR();
  }

  // ---- final state ----
  {
    const int m0 = w*16 + ((lane >> 4) << 2);
    const int nl = lane & 15;
    #pragma unroll
    for (int nt = 0; nt < 4; ++nt) {
      #pragma unroll
      for (int r = 0; r < 4; ++r)
        fsp[(size_t)(m0 + r) * DD + nt*16 + nl] = s[nt][r];
    }
  }
}

extern "C" void kernel_launch(void* const* d_in, const int* in_sizes, int n_in,
                              void* d_out, int out_size, void* d_ws, size_t ws_size,
                              hipStream_t stream) {
  const float* Q = (const float*)d_in[0];
  const float* K = (const float*)d_in[1];
  const float* V = (const float*)d_in[2];
  const float* G = (const float*)d_in[3];
  const float* B = (const float*)d_in[4];
  float* Out = (float*)d_out;
  float* FS  = Out + (size_t)NH * SEQL * DD;
  hipLaunchKernelGGL(gdn_chunk_kernel, dim3(NH*2), dim3(512), 0, stream,
                     Q, K, V, G, B, Out, FS);
}

// Round 3
// 356.727 us; speedup vs baseline: 5.9995x; 1.0031x over previous
//
#include <hip/hip_runtime.h>

typedef __attribute__((ext_vector_type(8)))  short short8;
typedef __attribute__((ext_vector_type(4)))  float f32x4;
typedef __attribute__((ext_vector_type(16))) float f32x16;
typedef __attribute__((ext_vector_type(4)))  unsigned short ushort4v;

#define NH   96
#define SEQL 2048
#define DD   128
#define CC   64
#define NCH  32
#define SK   136   // padded stride (ushorts) for 128-col bf16 mats
#define S64  72    // padded stride for 64-col bf16 mats
#define SLOT 4608  // 64*S64 ushorts per arena slot

__device__ __forceinline__ unsigned short f2bf(float f){
  union { float f; unsigned u; } v; v.f = f;
  unsigned r = v.u + 0x7FFFu + ((v.u >> 16) & 1u);
  return (unsigned short)(r >> 16);
}
__device__ __forceinline__ float bf2f(unsigned short u){
  union { unsigned u; float f; } v; v.u = ((unsigned)u) << 16; return v.f;
}

// A- or B-fragment for mfma_f32_32x32x16_bf16 from a row-major [outer][k] buffer.
// lane: outer = row0 + (l&31); k = 16*kt + 8*(l>>5) + j, j=0..7 (contiguous).
__device__ __forceinline__ short8 frg(const unsigned short* b, int stride, int row0, int kt, int lane){
  return *(const short8*)&b[(row0 + (lane & 31)) * stride + (kt << 4) + ((lane >> 5) << 3)];
}
// B-fragment of the identity matrix (in registers, no LDS).
__device__ __forceinline__ short8 ifrag(int n0, int kt, int lane){
  const int idx = n0 + (lane & 31) - (kt << 4) - ((lane >> 5) << 3);
  short8 v;
  #pragma unroll
  for (int e = 0; e < 8; ++e) v[e] = (short)((e == idx) ? 0x3F80 : 0);
  return v;
}

#define MM32(a,b,c) __builtin_amdgcn_mfma_f32_32x32x16_bf16(a,b,c,0,0,0)

template<int KTN>
__device__ __forceinline__ f32x16 gemm32(const unsigned short* A, int sa, int m0,
                                         const unsigned short* B, int sb, int n0,
                                         f32x16 acc, int lane){
  #pragma unroll
  for (int kt = 0; kt < KTN; ++kt)
    acc = MM32(frg(A, sa, m0, kt, lane), frg(B, sb, n0, kt, lane), acc);
  return acc;
}

// C/D layout (verified m74/m101): col = lane&31, row = (r&3) + 8*(r>>2) + 4*(lane>>5).
// "free store": acc of matrix Y -> writes Y^T row-major (quad per q, vectorized).
__device__ __forceinline__ void stq(unsigned short* buf, int stride, int n0, int m0, int lane, f32x16 v){
  const int nn = n0 + (lane & 31), hh = (lane >> 5) << 2;
  #pragma unroll
  for (int q = 0; q < 4; ++q) {
    ushort4v pv;
    #pragma unroll
    for (int s = 0; s < 4; ++s) pv[s] = f2bf(v[4*q + s]);
    *(ushort4v*)&buf[nn * stride + m0 + 8*q + hh] = pv;
  }
}
// quad init-read: acc[r] = Mat[row(r)][nn] where buf holds Mat^T row-major.
__device__ __forceinline__ f32x16 ldq(const unsigned short* buf, int stride, int n0, int m0, int lane){
  f32x16 a;
  const int nn = n0 + (lane & 31), hh = (lane >> 5) << 2;
  #pragma unroll
  for (int q = 0; q < 4; ++q) {
    ushort4v pv = *(const ushort4v*)&buf[nn * stride + m0 + 8*q + hh];
    #pragma unroll
    for (int s = 0; s < 4; ++s) a[4*q + s] = bf2f(pv[s]);
  }
  return a;
}

// barrier: drain LDS only (keeps global register-prefetch in flight)
#define BAR() do { asm volatile("s_waitcnt lgkmcnt(0)" ::: "memory"); __builtin_amdgcn_s_barrier(); } while(0)

__global__ __launch_bounds__(512, 1)
void gdn_chunk2(const float* __restrict__ Qg, const float* __restrict__ Kg,
                const float* __restrict__ Vg, const float* __restrict__ Gg,
                const float* __restrict__ Bg,
                float* __restrict__ Out, float* __restrict__ FS)
{
  __shared__ __align__(16) unsigned short sKc[64*SK];   // K~ row-major
  __shared__ __align__(16) unsigned short sQc[64*SK];   // Q~ row-major (w-scaled)
  __shared__ __align__(16) unsigned short sS0T[64*SK];  // S0^T row-major [v][d]
  __shared__ __align__(16) unsigned short sVc[64*S64];  // V row-major
  __shared__ __align__(16) unsigned short sVT[64*S64];  // V^T row-major
  __shared__ __align__(16) unsigned short sM[64*S64];   // M row-major
  __shared__ __align__(16) unsigned short sAr[8*SLOT];  // 8 aliased slots
  __shared__ float sbe2[2][64], swv2[2][64], swiv2[2][64];

  const int tid  = threadIdx.x;
  const int w    = tid >> 6;
  const int lane = tid & 63;
  const int half = w >> 2;        // 0: waves 0-3, 1: waves 4-7
  const int j    = w & 3;
  const int mt   = j >> 1, nt = j & 1;     // 64x64 tile of this wave
  const int mtS  = w >> 1, ntS = w & 1;    // state tile (128x64 -> 8 tiles)
  const int mtK  = w >> 2, ntK = w & 3;    // KT tile (64x128 C -> 8 tiles)

  const int head = blockIdx.x % NH;        // (head, head+96): same XCD (96%8==0)
  const int vh   = blockIdx.x / NH;

  const size_t rb = (size_t)head * SEQL * DD;
  const float* qp = Qg + rb;
  const float* kp = Kg + rb;
  const float* vp = Vg + rb + vh * 64;
  const float* gp = Gg + (size_t)head * SEQL;
  const float* bp = Bg + (size_t)head * SEQL;
  float* op  = Out + rb + vh * 64;
  float* fsp = FS + (size_t)head * DD * DD + vh * 64;

  const int lrow = tid >> 3;          // token row this thread stages
  const int c16  = (tid & 7) * 16;    // k/q col base
  const int c8   = (tid & 7) * 8;     // v col base

  unsigned short* const sl0 = sAr + 0*SLOT;
  unsigned short* const sl1 = sAr + 1*SLOT;
  unsigned short* const sl2 = sAr + 2*SLOT;
  unsigned short* const sl3 = sAr + 3*SLOT;
  unsigned short* const sl4 = sAr + 4*SLOT;
  unsigned short* const sl5 = sAr + 5*SLOT;
  unsigned short* const sl6 = sAr + 6*SLOT;  // KT uses sl6..sl7 (128 rows)
  unsigned short* const sl7 = sAr + 7*SLOT;

  f32x16 s   = {0.f,0.f,0.f,0.f,0.f,0.f,0.f,0.f,0.f,0.f,0.f,0.f,0.f,0.f,0.f,0.f};
  f32x16 oacc = s;

  f32x4 kr[4], qr[4], vr[2]; float gr = 0.f, br = 0.f;

  auto prefetch = [&](int t0p){
    const float* kb = kp + (size_t)(t0p + lrow) * DD + c16;
    const float* qb = qp + (size_t)(t0p + lrow) * DD + c16;
    const float* vb = vp + (size_t)(t0p + lrow) * DD + c8;
    #pragma unroll
    for (int i = 0; i < 4; ++i) { kr[i] = *(const f32x4*)(kb + 4*i); qr[i] = *(const f32x4*)(qb + 4*i); }
    #pragma unroll
    for (int i = 0; i < 2; ++i) vr[i] = *(const f32x4*)(vb + 4*i);
    if (w == 7) { gr = gp[t0p + lane]; br = bp[t0p + lane]; }
  };

  auto scan_to = [&](int p){
    if (w == 7) {
      float sc = gr;
      #pragma unroll
      for (int d = 1; d < 64; d <<= 1) { float t = __shfl_up(sc, d); if (lane >= d) sc += t; }
      swv2[p][lane]  = __expf(sc);
      swiv2[p][lane] = __expf(-sc);
      sbe2[p][lane]  = br;
    }
  };

  prefetch(0);
  scan_to(0);
  BAR();

  for (int tc = 0; tc < NCH; ++tc) {
    const int t0 = tc * CC;
    const int cur = tc & 1, nxt = cur ^ 1;

    // ================= P1: stage K~,Q~,V ; store S0^T ; prefetch next =================
    {
      float ssk = 0.f, ssq = 0.f;
      #pragma unroll
      for (int i = 0; i < 4; ++i) {
        ssk += kr[i][0]*kr[i][0] + kr[i][1]*kr[i][1] + kr[i][2]*kr[i][2] + kr[i][3]*kr[i][3];
        ssq += qr[i][0]*qr[i][0] + qr[i][1]*qr[i][1] + qr[i][2]*qr[i][2] + qr[i][3]*qr[i][3];
      }
      ssk += __shfl_xor(ssk, 1); ssk += __shfl_xor(ssk, 2); ssk += __shfl_xor(ssk, 4);
      ssq += __shfl_xor(ssq, 1); ssq += __shfl_xor(ssq, 2); ssq += __shfl_xor(ssq, 4);
      const float ik = 1.f / fmaxf(sqrtf(ssk), 1e-6f);
      const float iq = 0.08838834764831845f / fmaxf(sqrtf(ssq), 1e-6f) * swv2[cur][lrow];
      #pragma unroll
      for (int i = 0; i < 4; ++i) {
        ushort4v pk, pq;
        #pragma unroll
        for (int r = 0; r < 4; ++r) { pk[r] = f2bf(kr[i][r] * ik); pq[r] = f2bf(qr[i][r] * iq); }
        *(ushort4v*)&sKc[lrow*SK + c16 + 4*i] = pk;
        *(ushort4v*)&sQc[lrow*SK + c16 + 4*i] = pq;
      }
      #pragma unroll
      for (int i = 0; i < 2; ++i) {
        ushort4v pv;
        #pragma unroll
        for (int r = 0; r < 4; ++r) pv[r] = f2bf(vr[i][r]);
        *(ushort4v*)&sVc[lrow*S64 + c8 + 4*i] = pv;
      }
    }
    stq(sS0T, SK, 32*ntS, 32*mtS, lane, s);   // S0^T from state regs
    prefetch(tc < NCH-1 ? (tc+1)*CC : t0);
    BAR();

    // ================= P2: KK^T -> L0,R0,P0,P0T ; M^T-product -> M ====================
    if (half == 0) {
      f32x16 a = {0.f,0.f,0.f,0.f,0.f,0.f,0.f,0.f,0.f,0.f,0.f,0.f,0.f,0.f,0.f,0.f};
      a = gemm32<8>(sKc, SK, 32*mt, sKc, SK, 32*nt, a, lane);   // S_mn = k_m . k_n
      const int nn = 32*nt + (lane & 31), hh = (lane >> 5) << 2;
      #pragma unroll
      for (int q = 0; q < 4; ++q) {
        ushort4v pR, pL, pPT, pP;
        #pragma unroll
        for (int si = 0; si < 4; ++si) {
          const int r = 4*q + si, mm = 32*mt + 8*q + hh + si;
          const float S = a[r];
          const float av  = (mm > nn) ? sbe2[cur][mm]*swv2[cur][mm]*swiv2[cur][nn]*S : 0.f;
          const float atr = (nn > mm) ? sbe2[cur][nn]*swv2[cur][nn]*swiv2[cur][mm]*S : 0.f;
          pR[si]  = f2bf(av);                              // R0 = A^T rm
          pL[si]  = f2bf(atr);                             // L0 = A  rm
          pPT[si] = f2bf(((mm==nn)?1.f:0.f) - av);         // P0T rm
          pP[si]  = f2bf(((mm==nn)?1.f:0.f) - atr);        // P0  rm
        }
        const int off = nn*S64 + 32*mt + 8*q + hh;
        *(ushort4v*)&sl1[off] = pR;
        *(ushort4v*)&sl0[off] = pL;
        *(ushort4v*)&sl5[off] = pPT;
        *(ushort4v*)&sl4[off] = pP;
      }
    } else {
      // M^T-product: C = K~ . Q~^Tfr ; M[n][m] = (m<=n) ? C[m][n]*wi_m : 0
      f32x16 a = {0.f,0.f,0.f,0.f,0.f,0.f,0.f,0.f,0.f,0.f,0.f,0.f,0.f,0.f,0.f,0.f};
      a = gemm32<8>(sKc, SK, 32*mt, sQc, SK, 32*nt, a, lane);
      const int nn = 32*nt + (lane & 31), hh = (lane >> 5) << 2;
      #pragma unroll
      for (int q = 0; q < 4; ++q) {
        ushort4v pv;
        #pragma unroll
        for (int si = 0; si < 4; ++si) {
          const int r = 4*q + si, mm = 32*mt + 8*q + hh + si;
          pv[si] = f2bf((mm <= nn) ? a[r]*swiv2[cur][mm] : 0.f);
        }
        *(ushort4v*)&sM[nn*S64 + 32*mt + 8*q + hh] = pv;
      }
    }
    BAR();

    // ================= P3: lev0 squarings ; VT ; outS ================================
    if (half == 0) {
      f32x16 a = {0.f,0.f,0.f,0.f,0.f,0.f,0.f,0.f,0.f,0.f,0.f,0.f,0.f,0.f,0.f,0.f};
      a = gemm32<4>(sl0, S64, 32*mt, sl1, S64, 32*nt, a, lane);   // L0 * R0fr = A^2
      stq(sl3, S64, 32*nt, 32*mt, lane, a);                       // -> R1
      // VT = V^T via identity: C = V*I -> free-store V^T
      f32x16 b = {0.f,0.f,0.f,0.f,0.f,0.f,0.f,0.f,0.f,0.f,0.f,0.f,0.f,0.f,0.f,0.f};
      #pragma unroll
      for (int kk = 0; kk < 2; ++kk) {
        const int kt = 2*nt + kk;
        b = MM32(frg(sVc, S64, 32*mt, kt, lane), ifrag(32*nt, kt, lane), b);
      }
      stq(sVT, S64, 32*nt, 32*mt, lane, b);
    } else {
      f32x16 a = {0.f,0.f,0.f,0.f,0.f,0.f,0.f,0.f,0.f,0.f,0.f,0.f,0.f,0.f,0.f,0.f};
      a = gemm32<4>(sl1, S64, 32*mt, sl0, S64, 32*nt, a, lane);   // R0 * L0fr = (A^2)^T
      stq(sl2, S64, 32*nt, 32*mt, lane, a);                       // -> L1
      oacc = (f32x16){0.f,0.f,0.f,0.f,0.f,0.f,0.f,0.f,0.f,0.f,0.f,0.f,0.f,0.f,0.f,0.f};
      oacc = gemm32<8>(sQc, SK, 32*mt, sS0T, SK, 32*nt, oacc, lane);  // outS = Q~ . S0
    }
    BAR();

    // ================= P4..P6: levels 1..3 (both chains) =============================
    {
      unsigned short* const inL[3]   = { sl2, sl0, sl2 };
      unsigned short* const inR[3]   = { sl3, sl1, sl3 };
      unsigned short* const outL[3]  = { sl0, sl2, sl0 };
      unsigned short* const outR[3]  = { sl1, sl3, sl1 };
      unsigned short* const inP[3]   = { sl4, sl7, sl5 };
      unsigned short* const inPT[3]  = { sl5, sl6, sl4 };
      unsigned short* const outP[3]  = { sl7, sl5, sl7 };
      unsigned short* const outPT[3] = { sl6, sl4, sl6 };
      #pragma unroll
      for (int lev = 0; lev < 3; ++lev) {
        if (half == 0) {
          f32x16 a = {0.f,0.f,0.f,0.f,0.f,0.f,0.f,0.f,0.f,0.f,0.f,0.f,0.f,0.f,0.f,0.f};
          a = gemm32<4>(inL[lev], S64, 32*mt, inR[lev], S64, 32*nt, a, lane);
          stq(outR[lev], S64, 32*nt, 32*mt, lane, a);
          f32x16 p = ldq(inPT[lev], S64, 32*nt, 32*mt, lane);     // P_{j-1}
          p = gemm32<4>(inP[lev], S64, 32*mt, inR[lev], S64, 32*nt, p, lane); // + P*X
          stq(outPT[lev], S64, 32*nt, 32*mt, lane, p);            // -> P_j^T
        } else {
          f32x16 a = {0.f,0.f,0.f,0.f,0.f,0.f,0.f,0.f,0.f,0.f,0.f,0.f,0.f,0.f,0.f,0.f};
          a = gemm32<4>(inR[lev], S64, 32*mt, inL[lev], S64, 32*nt, a, lane);
          stq(outL[lev], S64, 32*nt, 32*mt, lane, a);
          f32x16 p = ldq(inP[lev], S64, 32*nt, 32*mt, lane);      // PT_{j-1}
          p = gemm32<4>(inR[lev], S64, 32*mt, inP[lev], S64, 32*nt, p, lane); // + X^T*P^T
          stq(outP[lev], S64, 32*nt, 32*mt, lane, p);             // -> P_j rm
        }
        BAR();
      }
    }

    // ================= P7: lev4 (R5 ; P4) ============================================
    if (half == 0) {
      f32x16 a = {0.f,0.f,0.f,0.f,0.f,0.f,0.f,0.f,0.f,0.f,0.f,0.f,0.f,0.f,0.f,0.f};
      a = gemm32<4>(sl0, S64, 32*mt, sl1, S64, 32*nt, a, lane);   // L4*R4fr = X32
      stq(sl2, S64, 32*nt, 32*mt, lane, a);                       // -> R5
    } else {
      f32x16 p = ldq(sl7, S64, 32*nt, 32*mt, lane);               // PT3 init (from P3 rm)
      p = gemm32<4>(sl1, S64, 32*mt, sl7, S64, 32*nt, p, lane);   // + R4 * P3fr
      stq(sl4, S64, 32*nt, 32*mt, lane, p);                       // -> P4 rm
    }
    BAR();

    // ================= P8: PT5 -> T2,T3 ; Z ; KT =====================================
    if (half == 0) {
      f32x16 p = ldq(sl4, S64, 32*nt, 32*mt, lane);               // PT4 init (from P4 rm)
      p = gemm32<4>(sl2, S64, 32*mt, sl4, S64, 32*nt, p, lane);   // + R5 * P4fr = T^T
      const int nn = 32*nt + (lane & 31), hh = (lane >> 5) << 2;
      #pragma unroll
      for (int q = 0; q < 4; ++q) {
        ushort4v p2, p3;
        #pragma unroll
        for (int si = 0; si < 4; ++si) {
          const int r = 4*q + si, mm = 32*mt + 8*q + hh + si;
          const float t = p[r];
          p2[si] = f2bf(-t * sbe2[cur][mm] * swv2[cur][mm]);      // T2[n][m]
          p3[si] = f2bf( t * sbe2[cur][mm]);                      // T3[n][m]
        }
        const int off = nn*S64 + 32*mt + 8*q + hh;
        *(ushort4v*)&sl1[off] = p2;
        *(ushort4v*)&sl5[off] = p3;
      }
    } else {
      f32x16 z = {0.f,0.f,0.f,0.f,0.f,0.f,0.f,0.f,0.f,0.f,0.f,0.f,0.f,0.f,0.f,0.f};
      z = gemm32<8>(sKc, SK, 32*mt, sS0T, SK, 32*nt, z, lane);    // Z = K~ . S0
      stq(sl0, S64, 32*nt, 32*mt, lane, z);                       // -> Z^T
    }
    {
      // KT = K~^T via identity: C = K~ * I128 -> free-store K^T (128 rows, sl6..sl7)
      f32x16 a = {0.f,0.f,0.f,0.f,0.f,0.f,0.f,0.f,0.f,0.f,0.f,0.f,0.f,0.f,0.f,0.f};
      #pragma unroll
      for (int kk = 0; kk < 2; ++kk) {
        const int kt = 2*ntK + kk;
        a = MM32(frg(sKc, SK, 32*mtK, kt, lane), ifrag(32*ntK, kt, lane), a);
      }
      stq(sl6, S64, 32*ntK, 32*mtK, lane, a);
    }
    BAR();

    // ================= P9: delta -> DT,DST ; decay ; next-chunk scan =================
    if (half == 0) {
      f32x16 d = {0.f,0.f,0.f,0.f,0.f,0.f,0.f,0.f,0.f,0.f,0.f,0.f,0.f,0.f,0.f,0.f};
      d = gemm32<4>(sl5, S64, 32*mt, sVT, S64, 32*nt, d, lane);   // T3 . V
      d = gemm32<4>(sl1, S64, 32*mt, sl0, S64, 32*nt, d, lane);   // + T2 . Z
      const int nn = 32*nt + (lane & 31), hh = (lane >> 5) << 2;
      const float w63 = swv2[cur][63];
      #pragma unroll
      for (int q = 0; q < 4; ++q) {
        ushort4v pt, ps;
        #pragma unroll
        for (int si = 0; si < 4; ++si) {
          const int r = 4*q + si, mm = 32*mt + 8*q + hh + si;
          pt[si] = f2bf(d[r]);
          ps[si] = f2bf(d[r] * w63 * swiv2[cur][mm]);
        }
        const int off = nn*S64 + 32*mt + 8*q + hh;
        *(ushort4v*)&sl3[off] = pt;   // DT  = delta^T
        *(ushort4v*)&sl2[off] = ps;   // DST = delta~^T
      }
    }
    scan_to(nxt);
    {
      const float w63 = swv2[cur][63];
      #pragma unroll
      for (int r = 0; r < 16; ++r) s[r] *= w63;
    }
    BAR();

    // ================= P10: S += K^T . delta~ ; out = outS + M.delta ================
    s = gemm32<4>(sl6, S64, 32*mtS, sl2, S64, 32*ntS, s, lane);
    if (half == 1) {
      f32x16 o = oacc;
      o = gemm32<4>(sM, S64, 32*mt, sl3, S64, 32*nt, o, lane);
      const int nn = 32*nt + (lane & 31), hh = (lane >> 5) << 2;
      #pragma unroll
      for (int q = 0; q < 4; ++q) {
        #pragma unroll
        for (int si = 0; si < 4; ++si) {
          const int mm = 32*mt + 8*q + hh + si;
          op[(size_t)(t0 + mm) * DD + nn] = o[4*q + si];
        }
      }
    }
    BAR();
  }

  // ---- final state ----
  {
    const int nn = 32*ntS + (lane & 31), hh = (lane >> 5) << 2;
    #pragma unroll
    for (int q = 0; q < 4; ++q) {
      #pragma unroll
      for (int si = 0; si < 4; ++si) {
        const int mm = 32*mtS + 8*q + hh + si;
        fsp[(size_t)mm * DD + nn] = s[4*q + si];
      }
    }
  }
}

extern "C" void kernel_launch(void* const* d_in, const int* in_sizes, int n_in,
                              void* d_out, int out_size, void* d_ws, size_t ws_size,
                              hipStream_t stream) {
  const float* Q = (const float*)d_in[0];
  const float* K = (const float*)d_in[1];
  const float* V = (const float*)d_in[2];
  const float* G = (const float*)d_in[3];
  const float* B = (const float*)d_in[4];
  float* Out = (float*)d_out;
  float* FS  = Out + (size_t)NH * SEQL * DD;
  hipLaunchKernelGGL(gdn_chunk2, dim3(NH*2), dim3(512), 0, stream,
                     Q, K, V, G, B, Out, FS);
}

// Round 4
// 286.784 us; speedup vs baseline: 7.4627x; 1.2439x over previous
//
#include <hip/hip_runtime.h>

typedef __attribute__((ext_vector_type(8)))  short short8;
typedef __attribute__((ext_vector_type(4)))  float f32x4;
typedef __attribute__((ext_vector_type(16))) float f32x16;
typedef __attribute__((ext_vector_type(4)))  unsigned short ushort4v;

#define NH   96
#define SEQL 2048
#define DD   128
#define CC   64
#define NCH  32
#define SK   136
#define S64  72
#define SLOT 4608

__device__ __forceinline__ unsigned short f2bf(float f){
  union { float f; unsigned u; } v; v.f = f;
  unsigned r = v.u + 0x7FFFu + ((v.u >> 16) & 1u);
  return (unsigned short)(r >> 16);
}
__device__ __forceinline__ float bf2f(unsigned short u){
  union { unsigned u; float f; } v; v.u = ((unsigned)u) << 16; return v.f;
}
__device__ __forceinline__ short8 frg(const unsigned short* b, int stride, int row0, int kt, int lane){
  return *(const short8*)&b[(row0 + (lane & 31)) * stride + (kt << 4) + ((lane >> 5) << 3)];
}
__device__ __forceinline__ short8 ifrag(int n0, int kt, int lane){
  const int idx = n0 + (lane & 31) - (kt << 4) - ((lane >> 5) << 3);
  short8 v;
  #pragma unroll
  for (int e = 0; e < 8; ++e) v[e] = (short)((e == idx) ? 0x3F80 : 0);
  return v;
}
#define MM32(A,B,C) __builtin_amdgcn_mfma_f32_32x32x16_bf16(A,B,C,0,0,0)
__device__ __forceinline__ f32x16 z16(){
  return (f32x16){0.f,0.f,0.f,0.f,0.f,0.f,0.f,0.f,0.f,0.f,0.f,0.f,0.f,0.f,0.f,0.f};
}
template<int KTN>
__device__ __forceinline__ f32x16 gemm32(const unsigned short* A, int sa, int m0,
                                         const unsigned short* B, int sb, int n0,
                                         f32x16 acc, int lane){
  #pragma unroll
  for (int kt = 0; kt < KTN; ++kt)
    acc = MM32(frg(A, sa, m0, kt, lane), frg(B, sb, n0, kt, lane), acc);
  return acc;
}
// store C^T row-major (bf16)
__device__ __forceinline__ void stq(unsigned short* buf, int stride, int n0, int m0, int lane, f32x16 v){
  const int nn = n0 + (lane & 31), hh = (lane >> 5) << 2;
  #pragma unroll
  for (int q = 0; q < 4; ++q) {
    ushort4v pv;
    #pragma unroll
    for (int s = 0; s < 4; ++s) pv[s] = f2bf(v[4*q + s]);
    *(ushort4v*)&buf[nn * stride + m0 + 8*q + hh] = pv;
  }
}
__device__ __forceinline__ void stqf(float* buf, int stride, int n0, int m0, int lane, f32x16 v){
  const int nn = n0 + (lane & 31), hh = (lane >> 5) << 2;
  #pragma unroll
  for (int q = 0; q < 4; ++q) {
    f32x4 pv;
    #pragma unroll
    for (int s = 0; s < 4; ++s) pv[s] = v[4*q + s];
    *(f32x4*)&buf[nn * stride + m0 + 8*q + hh] = pv;
  }
}
__device__ __forceinline__ f32x16 ldq(const unsigned short* buf, int stride, int n0, int m0, int lane){
  f32x16 a;
  const int nn = n0 + (lane & 31), hh = (lane >> 5) << 2;
  #pragma unroll
  for (int q = 0; q < 4; ++q) {
    ushort4v pv = *(const ushort4v*)&buf[nn * stride + m0 + 8*q + hh];
    #pragma unroll
    for (int s = 0; s < 4; ++s) a[4*q + s] = bf2f(pv[s]);
  }
  return a;
}
// init acc of C from P rm: acc[r] = P[n-col(lane)][m-row(r)]  (reads P^T into C-layout)
__device__ __forceinline__ f32x16 pinit(const unsigned short* lo, const unsigned short* hi,
                                        int nt, int m0, int lane){
  const unsigned short* base = (nt ? hi : lo) + (lane & 31) * S64;
  const int hh = (lane >> 5) << 2;
  f32x16 p;
  #pragma unroll
  for (int q = 0; q < 4; ++q) {
    ushort4v t = *(const ushort4v*)&base[m0 + 8*q + hh];
    #pragma unroll
    for (int s = 0; s < 4; ++s) p[4*q + s] = bf2f(t[s]);
  }
  return p;
}
#define BAR() do { asm volatile("s_waitcnt lgkmcnt(0)" ::: "memory"); __builtin_amdgcn_s_barrier(); } while(0)

// ---------------- workspace layout (ushort units per (head,chunk) record) ----------------
#define REC  36864
#define QOFF 0
#define WOFF 8192
#define UOFF 16384
#define KOFF 24576
#define MOFF 32768

// ================================ K1: per-chunk operators ================================
// arena offsets (ushorts)
#define AOF 0       /* sKc [64][136] -> later W'T [128][72] */
#define BOF 9216    /* sQc [64][136] -> later P-slots/T3/T2/U-quarters */
#define XS0 17920
#define XS1 22528
#define XS2 27136
#define XS3 31744
#define MRO 36352   /* M swizzled [64][64] -> later P-half / T-hi / U-q3 */

__global__ __launch_bounds__(256, 2)
void gdn_prep(const float* __restrict__ Qg, const float* __restrict__ Kg,
              const float* __restrict__ Vg, const float* __restrict__ Gg,
              const float* __restrict__ Bg,
              unsigned short* __restrict__ wsp, float* __restrict__ wcs)
{
  __shared__ unsigned short a[40448];
  __shared__ float s_swv[64], s_swiv[64], s_sbe[64];

  const int tid = threadIdx.x, w = tid >> 6, lane = tid & 63;
  const int mt = w >> 1, nt = w & 1;
  const int hc = blockIdx.x, head = hc >> 5, c = hc & 31;
  const int t0 = c * CC;
  const size_t rb = (size_t)head * SEQL * DD + (size_t)t0 * DD;
  const float* kp = Kg + rb;
  const float* qp = Qg + rb;
  const float* vp = Vg + rb;
  const float* gp = Gg + (size_t)head * SEQL + t0;
  const float* bp = Bg + (size_t)head * SEQL + t0;
  unsigned short* rec = wsp + (size_t)hc * REC;

  const int lrow = tid >> 2, cb = (tid & 3) * 32;
  const int cq16 = (tid & 3) * 16;

  // ---- ph01: load, scan, normalize, stage K~/Q~ (+Q~ -> global) ----
  f32x4 kr[8], qr[8], vr[8];
  #pragma unroll
  for (int i = 0; i < 8; ++i) {
    kr[i] = *(const f32x4*)(kp + (size_t)lrow * DD + cb + 4*i);
    qr[i] = *(const f32x4*)(qp + (size_t)lrow * DD + cb + 4*i);
    vr[i] = *(const f32x4*)(vp + (size_t)lrow * DD + cb + 4*i);
  }
  float gl = gp[lane], bl = bp[lane];
  float sc = gl;
  #pragma unroll
  for (int d = 1; d < 64; d <<= 1) { float t = __shfl_up(sc, d); if (lane >= d) sc += t; }
  float wv = __expf(sc);
  if (w == 0) { s_swv[lane] = wv; s_swiv[lane] = __expf(-sc); s_sbe[lane] = bl; }
  float ssk = 0.f, ssq = 0.f;
  #pragma unroll
  for (int i = 0; i < 8; ++i) {
    ssk += kr[i][0]*kr[i][0] + kr[i][1]*kr[i][1] + kr[i][2]*kr[i][2] + kr[i][3]*kr[i][3];
    ssq += qr[i][0]*qr[i][0] + qr[i][1]*qr[i][1] + qr[i][2]*qr[i][2] + qr[i][3]*qr[i][3];
  }
  ssk += __shfl_xor(ssk, 1); ssk += __shfl_xor(ssk, 2);
  ssq += __shfl_xor(ssq, 1); ssq += __shfl_xor(ssq, 2);
  const float ik = 1.f / fmaxf(sqrtf(ssk), 1e-6f);
  const float wl = __shfl(wv, lrow);
  const float iq = 0.08838834764831845f / fmaxf(sqrtf(ssq), 1e-6f) * wl;
  #pragma unroll
  for (int i = 0; i < 8; ++i) {
    ushort4v pk, pq;
    #pragma unroll
    for (int r = 0; r < 4; ++r) { pk[r] = f2bf(kr[i][r]*ik); pq[r] = f2bf(qr[i][r]*iq); }
    *(ushort4v*)&a[AOF + lrow*SK + cb + 4*i] = pk;
    *(ushort4v*)&a[BOF + lrow*SK + cb + 4*i] = pq;
    *(ushort4v*)(rec + QOFF + lrow*DD + cb + 4*i) = pq;
  }
  BAR();

  // ---- ph2: KK^T -> X0, X0T ; KQ~ -> M (swizzled) ----
  {
    f32x16 ckk = gemm32<8>(a+AOF, SK, 32*mt, a+AOF, SK, 32*nt, z16(), lane);
    f32x16 ckq = gemm32<8>(a+AOF, SK, 32*mt, a+BOF, SK, 32*nt, z16(), lane);
    const int nn = 32*nt + (lane & 31), hh = (lane >> 5) << 2;
    const float ben = s_sbe[nn], wvn = s_swv[nn], sin = s_swiv[nn];
    #pragma unroll
    for (int q = 0; q < 4; ++q) {
      ushort4v xT, xR, mv;
      #pragma unroll
      for (int si = 0; si < 4; ++si) {
        const int r = 4*q + si, mm = 32*mt + 8*q + hh + si;
        const float svm = s_swv[mm], sim = s_swiv[mm], bem = s_sbe[mm];
        xT[si] = (mm > nn) ? f2bf(bem*svm*sin*ckk[r]) : 0;
        xR[si] = (nn > mm) ? f2bf(ben*wvn*sim*ckk[r]) : 0;
        mv[si] = (mm <= nn) ? f2bf(ckq[r]*sim) : 0;
      }
      const int off = nn*S64 + 32*mt + 8*q + hh;
      *(ushort4v*)&a[XS1 + off] = xT;
      *(ushort4v*)&a[XS0 + off] = xR;
      const int blk = (32*mt + 8*q + hh) >> 2;
      *(ushort4v*)&a[MRO + nn*64 + ((blk ^ (nn & 15)) << 2)] = mv;
    }
  }
  BAR();

  // ---- ph3: X1 = X0^2 (dual) ; P0 = I - X0 ; M copy-out ----
  {
    f32x16 c1 = gemm32<4>(a+XS0, S64, 32*mt, a+XS1, S64, 32*nt, z16(), lane);
    f32x16 c2 = gemm32<4>(a+XS1, S64, 32*mt, a+XS0, S64, 32*nt, z16(), lane);
    stq(a+XS3, S64, 32*nt, 32*mt, lane, c1);
    stq(a+XS2, S64, 32*nt, 32*mt, lane, c2);
    unsigned short* p0 = a + ((lrow < 32) ? BOF : BOF+2304) + (lrow & 31)*S64;
    const unsigned short* x0 = a + XS0 + lrow*S64;
    #pragma unroll
    for (int jj = 0; jj < 2; ++jj) {
      short8 xv = *(const short8*)&x0[cq16 + 8*jj];
      short8 ov;
      #pragma unroll
      for (int e = 0; e < 8; ++e) {
        const int col = cq16 + 8*jj + e;
        ov[e] = (short)f2bf(((col == lrow) ? 1.f : 0.f) - bf2f((unsigned short)xv[e]));
      }
      *(short8*)&p0[cq16 + 8*jj] = ov;
    }
    #pragma unroll
    for (int b = 0; b < 4; ++b) {
      const int blk = (cq16 >> 2) + b, bh = blk ^ (lrow & 15);
      unsigned long long v = *(const unsigned long long*)&a[MRO + lrow*64 + bh*4];
      *(unsigned long long*)(rec + MOFF + lrow*64 + cq16 + b*4) = v;
    }
  }
  BAR();

  // ---- ph4..ph7: Neumann levels (X squaring dual + P products) ----
  #pragma unroll
  for (int lev = 0; lev < 4; ++lev) {
    const int sr = (lev & 1) ? XS0 : XS2;
    const int st = (lev & 1) ? XS1 : XS3;
    const int dr = (lev & 1) ? XS2 : XS0;
    const int dt = (lev & 1) ? XS3 : XS1;
    const int pp = lev & 1;
    unsigned short* plo_s = a + (pp ? BOF+SLOT : BOF);
    unsigned short* phi_s = a + (pp ? MRO : BOF+2304);
    unsigned short* plo_d = a + (pp ? BOF : BOF+SLOT);
    unsigned short* phi_d = a + (pp ? BOF+2304 : MRO);
    f32x16 c1 = gemm32<4>(a+sr, S64, 32*mt, a+st, S64, 32*nt, z16(), lane);
    if (lev < 3) {
      f32x16 c2 = gemm32<4>(a+st, S64, 32*mt, a+sr, S64, 32*nt, z16(), lane);
      stq(a+dt, S64, 32*nt, 32*mt, lane, c1);
      stq(a+dr, S64, 32*nt, 32*mt, lane, c2);
    } else {
      stq(a+XS2, S64, 32*nt, 32*mt, lane, c1);  // X5T
    }
    f32x16 p = pinit(plo_s, phi_s, nt, 32*mt, lane);
    p = gemm32<4>(a+st, S64, 32*mt, (nt ? phi_s : plo_s), S64, 0, p, lane);
    stq((nt ? phi_d : plo_d), S64, 0, 32*mt, lane, p);
    BAR();
  }

  // ---- ph8: T = P5 ; VT scatter from V-regs ----
  {
    f32x16 p = pinit(a+BOF, a+BOF+2304, nt, 32*mt, lane);
    p = gemm32<4>(a+XS2, S64, 32*mt, (nt ? a+BOF+2304 : a+BOF), S64, 0, p, lane);
    stq((nt ? a+MRO : a+BOF+SLOT), S64, 0, 32*mt, lane, p);   // T rm (parity1)
    #pragma unroll
    for (int i = 0; i < 8; ++i)
      #pragma unroll
      for (int r = 0; r < 4; ++r)
        a[XS0 + (cb + 4*i + r)*S64 + lrow] = f2bf(vr[i][r]);   // VT [128][72] over XS0..XS1
  }
  BAR();

  // ---- ph9: T2/T3 (in-place/new) ; KT idT -> XS2..XS3 ----
  {
    unsigned short* trow  = a + ((lrow < 32) ? BOF+SLOT : MRO) + (lrow & 31)*S64;
    unsigned short* t3row = a + ((lrow < 32) ? BOF : BOF+2304) + (lrow & 31)*S64;
    #pragma unroll
    for (int jj = 0; jj < 2; ++jj) {
      short8 tv = *(const short8*)&trow[cq16 + 8*jj];
      short8 o2, o3;
      #pragma unroll
      for (int e = 0; e < 8; ++e) {
        const int j = cq16 + 8*jj + e;
        const float t = bf2f((unsigned short)tv[e]);
        o2[e] = (short)f2bf(-t * s_sbe[j] * s_swv[j]);
        o3[e] = (short)f2bf( t * s_sbe[j]);
      }
      *(short8*)&trow[cq16 + 8*jj]  = o2;   // T2
      *(short8*)&t3row[cq16 + 8*jj] = o3;   // T3
    }
    #pragma unroll
    for (int j = 0; j < 2; ++j) {
      f32x16 ckt = z16();
      #pragma unroll
      for (int kk = 0; kk < 2; ++kk) {
        const int kt = 2*w + kk;
        ckt = MM32(frg(a+AOF, SK, 32*j, kt, lane), ifrag(32*w, kt, lane), ckt);
      }
      stq(a+XS2, S64, 32*w, 32*j, lane, ckt);   // KT [128][72]
    }
  }
  BAR();

  // ---- ph10: W'^T compute -> AOF ; U compute (held in regs) ----
  f32x16 uacc[2];
  {
    #pragma unroll
    for (int j = 0; j < 2; ++j) {
      f32x16 cw = gemm32<4>((j ? a+MRO : a+BOF+SLOT), S64, 0, a+XS2, S64, 32*w, z16(), lane);
      stq(a+AOF, S64, 32*w, 32*j, lane, cw);    // W'T rm [128][72]
      uacc[j] = gemm32<4>((j ? a+BOF+2304 : a+BOF), S64, 0, a+XS0, S64, 32*w, z16(), lane);
    }
  }
  BAR();

  // ---- ph11: W'T copy-out ; KST copy ; U stq -> quarters ; wc ----
  {
    const int r = tid >> 1, half = (tid & 1) * 32;
    const float wc = s_swv[63];
    #pragma unroll
    for (int j2 = 0; j2 < 4; ++j2) {
      short8 v8 = *(const short8*)&a[AOF + r*S64 + half + 8*j2];
      *(short8*)(rec + WOFF + r*64 + half + 8*j2) = v8;
      short8 kv = *(const short8*)&a[XS2 + r*S64 + half + 8*j2];
      short8 o;
      #pragma unroll
      for (int e = 0; e < 8; ++e) {
        const int tok = half + 8*j2 + e;
        o[e] = (short)f2bf(bf2f((unsigned short)kv[e]) * wc * s_swiv[tok]);
      }
      *(short8*)(rec + KOFF + r*64 + half + 8*j2) = o;
    }
    unsigned short* uq = a + ((w == 0) ? BOF : (w == 1) ? BOF+2304 : (w == 2) ? BOF+SLOT : MRO);
    stq(uq, S64, 0, 0, lane, uacc[0]);
    stq(uq, S64, 0, 32, lane, uacc[1]);
    if (tid == 0) wcs[hc] = wc;
  }
  BAR();

  // ---- ph12: U^T copy-out ----
  {
    const int r = tid >> 1, half = (tid & 1) * 32;
    const unsigned short* qb = a + ((r < 32) ? BOF : (r < 64) ? BOF+2304 : (r < 96) ? BOF+SLOT : MRO);
    #pragma unroll
    for (int j2 = 0; j2 < 4; ++j2) {
      short8 v8 = *(const short8*)&qb[(r & 31)*S64 + half + 8*j2];
      *(short8*)(rec + UOFF + r*64 + half + 8*j2) = v8;
    }
  }
}

// ================================ K2: sequential state scan ================================
#define K2W 0
#define K2K 8704
#define K2M 17920
#define K2U 22528
#define K2SET 27136
#define K2S0T 54272
#define K2DT  62976

__global__ __launch_bounds__(512, 1)
void gdn_scan(const unsigned short* __restrict__ wsp, const float* __restrict__ wcs,
              float* __restrict__ Out, float* __restrict__ FS)
{
  __shared__ unsigned short a[67584];
  __shared__ float s_ob[64*68];

  const int tid = threadIdx.x, w = tid >> 6, lane = tid & 63;
  const int head = blockIdx.x >> 1, vh = blockIdx.x & 1;
  const unsigned short* recs = wsp + (size_t)head * NCH * REC;
  float* op = Out + (size_t)head * SEQL * DD + vh * 64;

  f32x16 s = z16(), oq = z16();

  const int wr = tid & 127, wtg = tid >> 7;
  const int kr2 = tid >> 2, kc = (tid & 3) * 16;
  const int mr2 = tid >> 3, mc = (tid & 7) * 8;
  const int ur = tid & 63, utg = (tid >> 6) & 3;

  short8 stW0, stW1, stK0, stK1, stM, stU0, stU1;
  auto issue = [&](int c){
    const unsigned short* rec = recs + (size_t)c * REC;
    stW0 = *(const short8*)(rec + WOFF + wr*64 + wtg*16);
    stW1 = *(const short8*)(rec + WOFF + wr*64 + wtg*16 + 8);
    stK0 = *(const short8*)(rec + KOFF + kr2*64 + kc);
    stK1 = *(const short8*)(rec + KOFF + kr2*64 + kc + 8);
    stM  = *(const short8*)(rec + MOFF + mr2*64 + mc);
    if (tid >= 256) {
      stU0 = *(const short8*)(rec + UOFF + (vh*64 + ur)*64 + utg*16);
      stU1 = *(const short8*)(rec + UOFF + (vh*64 + ur)*64 + utg*16 + 8);
    }
  };
  auto dswrite = [&](int set){
    unsigned short* b = a + set * K2SET;
    #pragma unroll
    for (int e = 0; e < 8; ++e) {
      b[K2W + (wtg*16 + e)*SK + wr]     = (unsigned short)stW0[e];
      b[K2W + (wtg*16 + 8 + e)*SK + wr] = (unsigned short)stW1[e];
    }
    *(short8*)&b[K2K + kr2*S64 + kc]     = stK0;
    *(short8*)&b[K2K + kr2*S64 + kc + 8] = stK1;
    *(short8*)&b[K2M + mr2*S64 + mc]     = stM;
    if (tid >= 256) {
      #pragma unroll
      for (int e = 0; e < 8; ++e) {
        b[K2U + (utg*16 + e)*S64 + ur]     = (unsigned short)stU0[e];
        b[K2U + (utg*16 + 8 + e)*S64 + ur] = (unsigned short)stU1[e];
      }
    }
  };

  issue(0);
  stq(a+K2S0T, SK, 32*(w & 1), 32*(w >> 1), lane, s);   // S0 = 0
  dswrite(0);
  BAR();

  for (int c = 0; c < NCH; ++c) {
    const int cur = c & 1;
    const unsigned short* b = a + cur * K2SET;
    const unsigned short* rec = recs + (size_t)c * REC;
    const float wcf = wcs[head*NCH + c];

    // PH_B: waves0-3: Delta ; waves4-7: Oq^T (Q~ B-frags from global)
    if (w < 4) {
      const int mt = w >> 1, ntv = w & 1;
      const int nn = 32*ntv + (lane & 31), hh = (lane >> 5) << 2;
      float ui[16];
      #pragma unroll
      for (int q = 0; q < 4; ++q)
        #pragma unroll
        for (int si = 0; si < 4; ++si)
          ui[4*q+si] = bf2f(b[K2U + (32*mt + si + 8*q + hh)*S64 + nn]);
      f32x16 d = gemm32<8>(b+K2W, SK, 32*mt, a+K2S0T, SK, 32*ntv, z16(), lane);
      #pragma unroll
      for (int r = 0; r < 16; ++r) d[r] += ui[r];
      stq(a+K2DT, S64, 32*ntv, 32*mt, lane, d);
    } else {
      const int mt = (w - 4) >> 1, ntt = (w - 4) & 1;
      short8 qb[8];
      #pragma unroll
      for (int kt = 0; kt < 8; ++kt)
        qb[kt] = *(const short8*)(rec + QOFF + (32*ntt + (lane & 31))*DD + kt*16 + ((lane >> 5) << 3));
      f32x16 o = z16();
      #pragma unroll
      for (int kt = 0; kt < 8; ++kt)
        o = MM32(frg(a+K2S0T, SK, 32*mt, kt, lane), qb[kt], o);
      oq = o;
    }
    if (c < NCH-1) issue(c+1);
    BAR();

    // PH_C: S = wc*S + KST.Delta ; waves4-7: out^T = Oq^T + Delta^T.M^T -> s_ob
    {
      f32x16 sa;
      #pragma unroll
      for (int r = 0; r < 16; ++r) sa[r] = s[r] * wcf;
      s = gemm32<4>(b+K2K, S64, 32*(w >> 1), a+K2DT, S64, 32*(w & 1), sa, lane);
    }
    if (w >= 4) {
      const int mt = (w - 4) >> 1, ntt = (w - 4) & 1;
      f32x16 o = gemm32<4>(a+K2DT, S64, 32*mt, b+K2M, S64, 32*ntt, oq, lane);
      stqf(s_ob, 68, 32*ntt, 32*mt, lane, o);
    }
    BAR();

    // PH_A': stage next S0^T + next operand set ; out copy-out
    stq(a+K2S0T, SK, 32*(w & 1), 32*(w >> 1), lane, s);
    if (c < NCH-1) dswrite(cur ^ 1);
    {
      const int row = tid >> 3, c8 = (tid & 7) * 8;
      f32x4 v0 = *(const f32x4*)&s_ob[row*68 + c8];
      f32x4 v1 = *(const f32x4*)&s_ob[row*68 + c8 + 4];
      float* dst = op + (size_t)(c*CC + row) * DD + c8;
      *(f32x4*)dst = v0;
      *(f32x4*)(dst + 4) = v1;
    }
    BAR();
  }

  // final state
  {
    float* fsp = FS + (size_t)head * DD * DD + vh * 64;
    const int nn = 32*(w & 1) + (lane & 31), hh = (lane >> 5) << 2;
    #pragma unroll
    for (int q = 0; q < 4; ++q)
      #pragma unroll
      for (int si = 0; si < 4; ++si)
        fsp[(size_t)(32*(w >> 1) + si + 8*q + hh) * DD + nn] = s[4*q + si];
  }
}

// ================================ fallback (R3, verified) ================================
__global__ __launch_bounds__(512, 1)
void gdn_chunk2(const float* __restrict__ Qg, const float* __restrict__ Kg,
                const float* __restrict__ Vg, const float* __restrict__ Gg,
                const float* __restrict__ Bg,
                float* __restrict__ Out, float* __restrict__ FS)
{
  __shared__ __align__(16) unsigned short sKc[64*SK];
  __shared__ __align__(16) unsigned short sQc[64*SK];
  __shared__ __align__(16) unsigned short sS0T[64*SK];
  __shared__ __align__(16) unsigned short sVc[64*S64];
  __shared__ __align__(16) unsigned short sVT[64*S64];
  __shared__ __align__(16) unsigned short sM[64*S64];
  __shared__ __align__(16) unsigned short sAr[8*SLOT];
  __shared__ float sbe2[2][64], swv2[2][64], swiv2[2][64];

  const int tid  = threadIdx.x;
  const int w    = tid >> 6;
  const int lane = tid & 63;
  const int half = w >> 2;
  const int j    = w & 3;
  const int mt   = j >> 1, nt = j & 1;
  const int mtS  = w >> 1, ntS = w & 1;
  const int mtK  = w >> 2, ntK = w & 3;
  const int head = blockIdx.x % NH;
  const int vh   = blockIdx.x / NH;

  const size_t rb = (size_t)head * SEQL * DD;
  const float* qp = Qg + rb;
  const float* kp = Kg + rb;
  const float* vp = Vg + rb + vh * 64;
  const float* gp = Gg + (size_t)head * SEQL;
  const float* bp = Bg + (size_t)head * SEQL;
  float* op  = Out + rb + vh * 64;
  float* fsp = FS + (size_t)head * DD * DD + vh * 64;

  const int lrow = tid >> 3;
  const int c16  = (tid & 7) * 16;
  const int c8   = (tid & 7) * 8;

  unsigned short* const sl0 = sAr + 0*SLOT;
  unsigned short* const sl1 = sAr + 1*SLOT;
  unsigned short* const sl2 = sAr + 2*SLOT;
  unsigned short* const sl3 = sAr + 3*SLOT;
  unsigned short* const sl4 = sAr + 4*SLOT;
  unsigned short* const sl5 = sAr + 5*SLOT;
  unsigned short* const sl6 = sAr + 6*SLOT;
  unsigned short* const sl7 = sAr + 7*SLOT;

  f32x16 s = z16(), oacc = z16();
  f32x4 kr[4], qr[4], vr[2]; float gr = 0.f, br = 0.f;

  auto prefetch = [&](int t0p){
    const float* kb = kp + (size_t)(t0p + lrow) * DD + c16;
    const float* qb = qp + (size_t)(t0p + lrow) * DD + c16;
    const float* vb = vp + (size_t)(t0p + lrow) * DD + c8;
    #pragma unroll
    for (int i = 0; i < 4; ++i) { kr[i] = *(const f32x4*)(kb + 4*i); qr[i] = *(const f32x4*)(qb + 4*i); }
    #pragma unroll
    for (int i = 0; i < 2; ++i) vr[i] = *(const f32x4*)(vb + 4*i);
    if (w == 7) { gr = gp[t0p + lane]; br = bp[t0p + lane]; }
  };
  auto scan_to = [&](int p){
    if (w == 7) {
      float sc = gr;
      #pragma unroll
      for (int d = 1; d < 64; d <<= 1) { float t = __shfl_up(sc, d); if (lane >= d) sc += t; }
      swv2[p][lane]  = __expf(sc);
      swiv2[p][lane] = __expf(-sc);
      sbe2[p][lane]  = br;
    }
  };

  prefetch(0);
  scan_to(0);
  BAR();

  for (int tc = 0; tc < NCH; ++tc) {
    const int t0 = tc * CC;
    const int cur = tc & 1, nxt = cur ^ 1;
    {
      float ssk = 0.f, ssq = 0.f;
      #pragma unroll
      for (int i = 0; i < 4; ++i) {
        ssk += kr[i][0]*kr[i][0] + kr[i][1]*kr[i][1] + kr[i][2]*kr[i][2] + kr[i][3]*kr[i][3];
        ssq += qr[i][0]*qr[i][0] + qr[i][1]*qr[i][1] + qr[i][2]*qr[i][2] + qr[i][3]*qr[i][3];
      }
      ssk += __shfl_xor(ssk, 1); ssk += __shfl_xor(ssk, 2); ssk += __shfl_xor(ssk, 4);
      ssq += __shfl_xor(ssq, 1); ssq += __shfl_xor(ssq, 2); ssq += __shfl_xor(ssq, 4);
      const float ik = 1.f / fmaxf(sqrtf(ssk), 1e-6f);
      const float iq = 0.08838834764831845f / fmaxf(sqrtf(ssq), 1e-6f) * swv2[cur][lrow];
      #pragma unroll
      for (int i = 0; i < 4; ++i) {
        ushort4v pk, pq;
        #pragma unroll
        for (int r = 0; r < 4; ++r) { pk[r] = f2bf(kr[i][r] * ik); pq[r] = f2bf(qr[i][r] * iq); }
        *(ushort4v*)&sKc[lrow*SK + c16 + 4*i] = pk;
        *(ushort4v*)&sQc[lrow*SK + c16 + 4*i] = pq;
      }
      #pragma unroll
      for (int i = 0; i < 2; ++i) {
        ushort4v pv;
        #pragma unroll
        for (int r = 0; r < 4; ++r) pv[r] = f2bf(vr[i][r]);
        *(ushort4v*)&sVc[lrow*S64 + c8 + 4*i] = pv;
      }
    }
    stq(sS0T, SK, 32*ntS, 32*mtS, lane, s);
    prefetch(tc < NCH-1 ? (tc+1)*CC : t0);
    BAR();

    if (half == 0) {
      f32x16 aa = gemm32<8>(sKc, SK, 32*mt, sKc, SK, 32*nt, z16(), lane);
      const int nn = 32*nt + (lane & 31), hh = (lane >> 5) << 2;
      #pragma unroll
      for (int q = 0; q < 4; ++q) {
        ushort4v pR, pL, pPT, pP;
        #pragma unroll
        for (int si = 0; si < 4; ++si) {
          const int r = 4*q + si, mm = 32*mt + 8*q + hh + si;
          const float S = aa[r];
          const float av  = (mm > nn) ? sbe2[cur][mm]*swv2[cur][mm]*swiv2[cur][nn]*S : 0.f;
          const float atr = (nn > mm) ? sbe2[cur][nn]*swv2[cur][nn]*swiv2[cur][mm]*S : 0.f;
          pR[si]  = f2bf(av);
          pL[si]  = f2bf(atr);
          pPT[si] = f2bf(((mm==nn)?1.f:0.f) - av);
          pP[si]  = f2bf(((mm==nn)?1.f:0.f) - atr);
        }
        const int off = nn*S64 + 32*mt + 8*q + hh;
        *(ushort4v*)&sl1[off] = pR;
        *(ushort4v*)&sl0[off] = pL;
        *(ushort4v*)&sl5[off] = pPT;
        *(ushort4v*)&sl4[off] = pP;
      }
    } else {
      f32x16 aa = gemm32<8>(sKc, SK, 32*mt, sQc, SK, 32*nt, z16(), lane);
      const int nn = 32*nt + (lane & 31), hh = (lane >> 5) << 2;
      #pragma unroll
      for (int q = 0; q < 4; ++q) {
        ushort4v pv;
        #pragma unroll
        for (int si = 0; si < 4; ++si) {
          const int r = 4*q + si, mm = 32*mt + 8*q + hh + si;
          pv[si] = f2bf((mm <= nn) ? aa[r]*swiv2[cur][mm] : 0.f);
        }
        *(ushort4v*)&sM[nn*S64 + 32*mt + 8*q + hh] = pv;
      }
    }
    BAR();

    if (half == 0) {
      f32x16 aa = gemm32<4>(sl0, S64, 32*mt, sl1, S64, 32*nt, z16(), lane);
      stq(sl3, S64, 32*nt, 32*mt, lane, aa);
      f32x16 bb = z16();
      #pragma unroll
      for (int kk = 0; kk < 2; ++kk) {
        const int kt = 2*nt + kk;
        bb = MM32(frg(sVc, S64, 32*mt, kt, lane), ifrag(32*nt, kt, lane), bb);
      }
      stq(sVT, S64, 32*nt, 32*mt, lane, bb);
    } else {
      f32x16 aa = gemm32<4>(sl1, S64, 32*mt, sl0, S64, 32*nt, z16(), lane);
      stq(sl2, S64, 32*nt, 32*mt, lane, aa);
      oacc = gemm32<8>(sQc, SK, 32*mt, sS0T, SK, 32*nt, z16(), lane);
    }
    BAR();

    {
      unsigned short* const inL[3]   = { sl2, sl0, sl2 };
      unsigned short* const inR[3]   = { sl3, sl1, sl3 };
      unsigned short* const outL[3]  = { sl0, sl2, sl0 };
      unsigned short* const outR[3]  = { sl1, sl3, sl1 };
      unsigned short* const inP[3]   = { sl4, sl7, sl5 };
      unsigned short* const inPT[3]  = { sl5, sl6, sl4 };
      unsigned short* const outP[3]  = { sl7, sl5, sl7 };
      unsigned short* const outPT[3] = { sl6, sl4, sl6 };
      #pragma unroll
      for (int lev = 0; lev < 3; ++lev) {
        if (half == 0) {
          f32x16 aa = gemm32<4>(inL[lev], S64, 32*mt, inR[lev], S64, 32*nt, z16(), lane);
          stq(outR[lev], S64, 32*nt, 32*mt, lane, aa);
          f32x16 p = ldq(inPT[lev], S64, 32*nt, 32*mt, lane);
          p = gemm32<4>(inP[lev], S64, 32*mt, inR[lev], S64, 32*nt, p, lane);
          stq(outPT[lev], S64, 32*nt, 32*mt, lane, p);
        } else {
          f32x16 aa = gemm32<4>(inR[lev], S64, 32*mt, inL[lev], S64, 32*nt, z16(), lane);
          stq(outL[lev], S64, 32*nt, 32*mt, lane, aa);
          f32x16 p = ldq(inP[lev], S64, 32*nt, 32*mt, lane);
          p = gemm32<4>(inR[lev], S64, 32*mt, inP[lev], S64, 32*nt, p, lane);
          stq(outP[lev], S64, 32*nt, 32*mt, lane, p);
        }
        BAR();
      }
    }

    if (half == 0) {
      f32x16 aa = gemm32<4>(sl0, S64, 32*mt, sl1, S64, 32*nt, z16(), lane);
      stq(sl2, S64, 32*nt, 32*mt, lane, aa);
    } else {
      f32x16 p = ldq(sl7, S64, 32*nt, 32*mt, lane);
      p = gemm32<4>(sl1, S64, 32*mt, sl7, S64, 32*nt, p, lane);
      stq(sl4, S64, 32*nt, 32*mt, lane, p);
    }
    BAR();

    if (half == 0) {
      f32x16 p = ldq(sl4, S64, 32*nt, 32*mt, lane);
      p = gemm32<4>(sl2, S64, 32*mt, sl4, S64, 32*nt, p, lane);
      const int nn = 32*nt + (lane & 31), hh = (lane >> 5) << 2;
      #pragma unroll
      for (int q = 0; q < 4; ++q) {
        ushort4v p2, p3;
        #pragma unroll
        for (int si = 0; si < 4; ++si) {
          const int r = 4*q + si, mm = 32*mt + 8*q + hh + si;
          const float t = p[r];
          p2[si] = f2bf(-t * sbe2[cur][mm] * swv2[cur][mm]);
          p3[si] = f2bf( t * sbe2[cur][mm]);
        }
        const int off = nn*S64 + 32*mt + 8*q + hh;
        *(ushort4v*)&sl1[off] = p2;
        *(ushort4v*)&sl5[off] = p3;
      }
    } else {
      f32x16 zz = gemm32<8>(sKc, SK, 32*mt, sS0T, SK, 32*nt, z16(), lane);
      stq(sl0, S64, 32*nt, 32*mt, lane, zz);
    }
    {
      f32x16 aa = z16();
      #pragma unroll
      for (int kk = 0; kk < 2; ++kk) {
        const int kt = 2*ntK + kk;
        aa = MM32(frg(sKc, SK, 32*mtK, kt, lane), ifrag(32*ntK, kt, lane), aa);
      }
      stq(sl6, S64, 32*ntK, 32*mtK, lane, aa);
    }
    BAR();

    if (half == 0) {
      f32x16 d = gemm32<4>(sl5, S64, 32*mt, sVT, S64, 32*nt, z16(), lane);
      d = gemm32<4>(sl1, S64, 32*mt, sl0, S64, 32*nt, d, lane);
      const int nn = 32*nt + (lane & 31), hh = (lane >> 5) << 2;
      const float w63 = swv2[cur][63];
      #pragma unroll
      for (int q = 0; q < 4; ++q) {
        ushort4v pt, ps;
        #pragma unroll
        for (int si = 0; si < 4; ++si) {
          const int r = 4*q + si, mm = 32*mt + 8*q + hh + si;
          pt[si] = f2bf(d[r]);
          ps[si] = f2bf(d[r] * w63 * swiv2[cur][mm]);
        }
        const int off = nn*S64 + 32*mt + 8*q + hh;
        *(ushort4v*)&sl3[off] = pt;
        *(ushort4v*)&sl2[off] = ps;
      }
    }
    scan_to(nxt);
    {
      const float w63 = swv2[cur][63];
      #pragma unroll
      for (int r = 0; r < 16; ++r) s[r] *= w63;
    }
    BAR();

    s = gemm32<4>(sl6, S64, 32*mtS, sl2, S64, 32*ntS, s, lane);
    if (half == 1) {
      f32x16 o = oacc;
      o = gemm32<4>(sM, S64, 32*mt, sl3, S64, 32*nt, o, lane);
      const int nn = 32*nt + (lane & 31), hh = (lane >> 5) << 2;
      #pragma unroll
      for (int q = 0; q < 4; ++q)
        #pragma unroll
        for (int si = 0; si < 4; ++si)
          op[(size_t)(t0 + 32*mt + 8*q + hh + si) * DD + nn] = o[4*q + si];
    }
    BAR();
  }

  {
    const int nn = 32*ntS + (lane & 31), hh = (lane >> 5) << 2;
    #pragma unroll
    for (int q = 0; q < 4; ++q)
      #pragma unroll
      for (int si = 0; si < 4; ++si)
        fsp[(size_t)(32*mtS + 8*q + hh + si) * DD + nn] = s[4*q + si];
  }
}

extern "C" void kernel_launch(void* const* d_in, const int* in_sizes, int n_in,
                              void* d_out, int out_size, void* d_ws, size_t ws_size,
                              hipStream_t stream) {
  const float* Q = (const float*)d_in[0];
  const float* K = (const float*)d_in[1];
  const float* V = (const float*)d_in[2];
  const float* G = (const float*)d_in[3];
  const float* B = (const float*)d_in[4];
  float* Out = (float*)d_out;
  float* FS  = Out + (size_t)NH * SEQL * DD;

  const size_t WS_NEED = (size_t)NH * NCH * REC * 2 + (size_t)NH * NCH * 4;
  if (ws_size >= WS_NEED) {
    unsigned short* wsp = (unsigned short*)d_ws;
    float* wcs = (float*)(wsp + (size_t)NH * NCH * REC);
    hipLaunchKernelGGL(gdn_prep, dim3(NH*NCH), dim3(256), 0, stream, Q, K, V, G, B, wsp, wcs);
    hipLaunchKernelGGL(gdn_scan, dim3(NH*2), dim3(512), 0, stream, wsp, wcs, Out, FS);
  } else {
    hipLaunchKernelGGL(gdn_chunk2, dim3(NH*2), dim3(512), 0, stream, Q, K, V, G, B, Out, FS);
  }
}

// Round 5
// 254.804 us; speedup vs baseline: 8.3993x; 1.1255x over previous
//
#include <hip/hip_runtime.h>

typedef __attribute__((ext_vector_type(8)))  short short8;
typedef __attribute__((ext_vector_type(4)))  float f32x4;
typedef __attribute__((ext_vector_type(16))) float f32x16;
typedef __attribute__((ext_vector_type(4)))  unsigned short ushort4v;

#define NH   96
#define SEQL 2048
#define DD   128
#define CC   64
#define NCH  32
#define SK   136
#define S64  72
#define SLOT 4608

__device__ __forceinline__ unsigned short f2bf(float f){
  union { float f; unsigned u; } v; v.f = f;
  unsigned r = v.u + 0x7FFFu + ((v.u >> 16) & 1u);
  return (unsigned short)(r >> 16);
}
__device__ __forceinline__ float bf2f(unsigned short u){
  union { unsigned u; float f; } v; v.u = ((unsigned)u) << 16; return v.f;
}
__device__ __forceinline__ short8 frg(const unsigned short* b, int stride, int row0, int kt, int lane){
  return *(const short8*)&b[(row0 + (lane & 31)) * stride + (kt << 4) + ((lane >> 5) << 3)];
}
__device__ __forceinline__ short8 ifrag(int n0, int kt, int lane){
  const int idx = n0 + (lane & 31) - (kt << 4) - ((lane >> 5) << 3);
  short8 v;
  #pragma unroll
  for (int e = 0; e < 8; ++e) v[e] = (short)((e == idx) ? 0x3F80 : 0);
  return v;
}
#define MM32(A,B,C) __builtin_amdgcn_mfma_f32_32x32x16_bf16(A,B,C,0,0,0)
__device__ __forceinline__ f32x16 z16(){
  return (f32x16){0.f,0.f,0.f,0.f,0.f,0.f,0.f,0.f,0.f,0.f,0.f,0.f,0.f,0.f,0.f,0.f};
}
template<int KTN>
__device__ __forceinline__ f32x16 gemm32(const unsigned short* A, int sa, int m0,
                                         const unsigned short* B, int sb, int n0,
                                         f32x16 acc, int lane){
  #pragma unroll
  for (int kt = 0; kt < KTN; ++kt)
    acc = MM32(frg(A, sa, m0, kt, lane), frg(B, sb, n0, kt, lane), acc);
  return acc;
}
// store C^T row-major (bf16)
__device__ __forceinline__ void stq(unsigned short* buf, int stride, int n0, int m0, int lane, f32x16 v){
  const int nn = n0 + (lane & 31), hh = (lane >> 5) << 2;
  #pragma unroll
  for (int q = 0; q < 4; ++q) {
    ushort4v pv;
    #pragma unroll
    for (int s = 0; s < 4; ++s) pv[s] = f2bf(v[4*q + s]);
    *(ushort4v*)&buf[nn * stride + m0 + 8*q + hh] = pv;
  }
}
__device__ __forceinline__ void stqf(float* buf, int stride, int n0, int m0, int lane, f32x16 v){
  const int nn = n0 + (lane & 31), hh = (lane >> 5) << 2;
  #pragma unroll
  for (int q = 0; q < 4; ++q) {
    f32x4 pv;
    #pragma unroll
    for (int s = 0; s < 4; ++s) pv[s] = v[4*q + s];
    *(f32x4*)&buf[nn * stride + m0 + 8*q + hh] = pv;
  }
}
__device__ __forceinline__ f32x16 ldq(const unsigned short* buf, int stride, int n0, int m0, int lane){
  f32x16 a;
  const int nn = n0 + (lane & 31), hh = (lane >> 5) << 2;
  #pragma unroll
  for (int q = 0; q < 4; ++q) {
    ushort4v pv = *(const ushort4v*)&buf[nn * stride + m0 + 8*q + hh];
    #pragma unroll
    for (int s = 0; s < 4; ++s) a[4*q + s] = bf2f(pv[s]);
  }
  return a;
}
__device__ __forceinline__ f32x16 pinit(const unsigned short* lo, const unsigned short* hi,
                                        int nt, int m0, int lane){
  const unsigned short* base = (nt ? hi : lo) + (lane & 31) * S64;
  const int hh = (lane >> 5) << 2;
  f32x16 p;
  #pragma unroll
  for (int q = 0; q < 4; ++q) {
    ushort4v t = *(const ushort4v*)&base[m0 + 8*q + hh];
    #pragma unroll
    for (int s = 0; s < 4; ++s) p[4*q + s] = bf2f(t[s]);
  }
  return p;
}
#define BAR() do { asm volatile("s_waitcnt lgkmcnt(0)" ::: "memory"); __builtin_amdgcn_s_barrier(); } while(0)

// ---------------- workspace layout (ushort units per (head,chunk) record) ----------------
#define REC  36864
#define QOFF 0
#define WOFF 8192     // W' row-major [64 tok][128 dk]
#define UOFF 16384    // U^T row-major [128 v][64 tok]
#define KOFF 24576    // KST row-major [128 dk][64 tok]
#define MOFF 32768    // M row-major [64 out-tok][64 src-tok]

// ================================ K1: per-chunk operators ================================
#define AOF 0
#define BOF 9216
#define XS0 17920
#define XS1 22528
#define XS2 27136
#define XS3 31744
#define MRO 36352

__global__ __launch_bounds__(256, 2)
void gdn_prep(const float* __restrict__ Qg, const float* __restrict__ Kg,
              const float* __restrict__ Vg, const float* __restrict__ Gg,
              const float* __restrict__ Bg,
              unsigned short* __restrict__ wsp, float* __restrict__ wcs)
{
  __shared__ unsigned short a[40448];
  __shared__ float s_swv[64], s_swiv[64], s_sbe[64];

  const int tid = threadIdx.x, w = tid >> 6, lane = tid & 63;
  const int mt = w >> 1, nt = w & 1;
  const int hc = blockIdx.x, head = hc >> 5, c = hc & 31;
  const int t0 = c * CC;
  const size_t rb = (size_t)head * SEQL * DD + (size_t)t0 * DD;
  const float* kp = Kg + rb;
  const float* qp = Qg + rb;
  const float* vp = Vg + rb;
  const float* gp = Gg + (size_t)head * SEQL + t0;
  const float* bp = Bg + (size_t)head * SEQL + t0;
  unsigned short* rec = wsp + (size_t)hc * REC;

  const int lrow = tid >> 2, cb = (tid & 3) * 32;
  const int cq16 = (tid & 3) * 16;

  // ---- ph01: load, scan, normalize, stage K~/Q~ (+Q~ -> global) ----
  f32x4 kr[8], qr[8], vr[8];
  #pragma unroll
  for (int i = 0; i < 8; ++i) {
    kr[i] = *(const f32x4*)(kp + (size_t)lrow * DD + cb + 4*i);
    qr[i] = *(const f32x4*)(qp + (size_t)lrow * DD + cb + 4*i);
    vr[i] = *(const f32x4*)(vp + (size_t)lrow * DD + cb + 4*i);
  }
  float gl = gp[lane], bl = bp[lane];
  float sc = gl;
  #pragma unroll
  for (int d = 1; d < 64; d <<= 1) { float t = __shfl_up(sc, d); if (lane >= d) sc += t; }
  float wv = __expf(sc);
  if (w == 0) { s_swv[lane] = wv; s_swiv[lane] = __expf(-sc); s_sbe[lane] = bl; }
  float ssk = 0.f, ssq = 0.f;
  #pragma unroll
  for (int i = 0; i < 8; ++i) {
    ssk += kr[i][0]*kr[i][0] + kr[i][1]*kr[i][1] + kr[i][2]*kr[i][2] + kr[i][3]*kr[i][3];
    ssq += qr[i][0]*qr[i][0] + qr[i][1]*qr[i][1] + qr[i][2]*qr[i][2] + qr[i][3]*qr[i][3];
  }
  ssk += __shfl_xor(ssk, 1); ssk += __shfl_xor(ssk, 2);
  ssq += __shfl_xor(ssq, 1); ssq += __shfl_xor(ssq, 2);
  const float ik = 1.f / fmaxf(sqrtf(ssk), 1e-6f);
  const float wl = __shfl(wv, lrow);
  const float iq = 0.08838834764831845f / fmaxf(sqrtf(ssq), 1e-6f) * wl;
  #pragma unroll
  for (int i = 0; i < 8; ++i) {
    ushort4v pk, pq;
    #pragma unroll
    for (int r = 0; r < 4; ++r) { pk[r] = f2bf(kr[i][r]*ik); pq[r] = f2bf(qr[i][r]*iq); }
    *(ushort4v*)&a[AOF + lrow*SK + cb + 4*i] = pk;
    *(ushort4v*)&a[BOF + lrow*SK + cb + 4*i] = pq;
    *(ushort4v*)(rec + QOFF + lrow*DD + cb + 4*i) = pq;
  }
  BAR();

  // ---- ph2: KK^T -> X0, X0T ; KQ~ -> M (swizzled) ----
  {
    f32x16 ckk = gemm32<8>(a+AOF, SK, 32*mt, a+AOF, SK, 32*nt, z16(), lane);
    f32x16 ckq = gemm32<8>(a+AOF, SK, 32*mt, a+BOF, SK, 32*nt, z16(), lane);
    const int nn = 32*nt + (lane & 31), hh = (lane >> 5) << 2;
    const float ben = s_sbe[nn], wvn = s_swv[nn], sin = s_swiv[nn];
    #pragma unroll
    for (int q = 0; q < 4; ++q) {
      ushort4v xT, xR, mv;
      #pragma unroll
      for (int si = 0; si < 4; ++si) {
        const int r = 4*q + si, mm = 32*mt + 8*q + hh + si;
        const float svm = s_swv[mm], sim = s_swiv[mm], bem = s_sbe[mm];
        xT[si] = (mm > nn) ? f2bf(bem*svm*sin*ckk[r]) : 0;
        xR[si] = (nn > mm) ? f2bf(ben*wvn*sim*ckk[r]) : 0;
        mv[si] = (mm <= nn) ? f2bf(ckq[r]*sim) : 0;
      }
      const int off = nn*S64 + 32*mt + 8*q + hh;
      *(ushort4v*)&a[XS1 + off] = xT;
      *(ushort4v*)&a[XS0 + off] = xR;
      const int blk = (32*mt + 8*q + hh) >> 2;
      *(ushort4v*)&a[MRO + nn*64 + ((blk ^ (nn & 15)) << 2)] = mv;
    }
  }
  BAR();

  // ---- ph3: X1 = X0^2 (dual) ; P0 = I - X0 ; M copy-out ----
  {
    f32x16 c1 = gemm32<4>(a+XS0, S64, 32*mt, a+XS1, S64, 32*nt, z16(), lane);
    f32x16 c2 = gemm32<4>(a+XS1, S64, 32*mt, a+XS0, S64, 32*nt, z16(), lane);
    stq(a+XS3, S64, 32*nt, 32*mt, lane, c1);
    stq(a+XS2, S64, 32*nt, 32*mt, lane, c2);
    unsigned short* p0 = a + ((lrow < 32) ? BOF : BOF+2304) + (lrow & 31)*S64;
    const unsigned short* x0 = a + XS0 + lrow*S64;
    #pragma unroll
    for (int jj = 0; jj < 2; ++jj) {
      short8 xv = *(const short8*)&x0[cq16 + 8*jj];
      short8 ov;
      #pragma unroll
      for (int e = 0; e < 8; ++e) {
        const int col = cq16 + 8*jj + e;
        ov[e] = (short)f2bf(((col == lrow) ? 1.f : 0.f) - bf2f((unsigned short)xv[e]));
      }
      *(short8*)&p0[cq16 + 8*jj] = ov;
    }
    #pragma unroll
    for (int b = 0; b < 4; ++b) {
      const int blk = (cq16 >> 2) + b, bh = blk ^ (lrow & 15);
      unsigned long long v = *(const unsigned long long*)&a[MRO + lrow*64 + bh*4];
      *(unsigned long long*)(rec + MOFF + lrow*64 + cq16 + b*4) = v;
    }
  }
  BAR();

  // ---- ph4..ph5: Neumann levels 0..1 (4-factor truncation; A^16 terms ~1e-13) ----
  #pragma unroll
  for (int lev = 0; lev < 2; ++lev) {
    const int sr = (lev & 1) ? XS0 : XS2;
    const int st = (lev & 1) ? XS1 : XS3;
    const int dr = (lev & 1) ? XS2 : XS0;
    const int dt = (lev & 1) ? XS3 : XS1;
    const int pp = lev & 1;
    unsigned short* plo_s = a + (pp ? BOF+SLOT : BOF);
    unsigned short* phi_s = a + (pp ? MRO : BOF+2304);
    unsigned short* plo_d = a + (pp ? BOF : BOF+SLOT);
    unsigned short* phi_d = a + (pp ? BOF+2304 : MRO);
    f32x16 c1 = gemm32<4>(a+sr, S64, 32*mt, a+st, S64, 32*nt, z16(), lane);
    if (lev < 1) {
      f32x16 c2 = gemm32<4>(a+st, S64, 32*mt, a+sr, S64, 32*nt, z16(), lane);
      stq(a+dt, S64, 32*nt, 32*mt, lane, c1);
      stq(a+dr, S64, 32*nt, 32*mt, lane, c2);
    } else {
      stq(a+XS2, S64, 32*nt, 32*mt, lane, c1);  // L3 = A^8 rm
    }
    f32x16 p = pinit(plo_s, phi_s, nt, 32*mt, lane);
    p = gemm32<4>(a+st, S64, 32*mt, (nt ? phi_s : plo_s), S64, 0, p, lane);
    stq((nt ? phi_d : plo_d), S64, 0, 32*mt, lane, p);
    BAR();
  }

  // ---- ph6: T = P2 + A^8*P2 ; VT scatter from V-regs ----
  {
    f32x16 p = pinit(a+BOF, a+BOF+2304, nt, 32*mt, lane);
    p = gemm32<4>(a+XS2, S64, 32*mt, (nt ? a+BOF+2304 : a+BOF), S64, 0, p, lane);
    stq((nt ? a+MRO : a+BOF+SLOT), S64, 0, 32*mt, lane, p);   // T rm halves
    #pragma unroll
    for (int i = 0; i < 8; ++i)
      #pragma unroll
      for (int r = 0; r < 4; ++r)
        a[XS0 + (cb + 4*i + r)*S64 + lrow] = f2bf(vr[i][r]);   // VT [128][72] over XS0..XS1
  }
  BAR();

  // ---- ph7: T2/T3 ; KT idT -> XS2..XS3 ----
  {
    unsigned short* trow  = a + ((lrow < 32) ? BOF+SLOT : MRO) + (lrow & 31)*S64;
    unsigned short* t3row = a + ((lrow < 32) ? BOF : BOF+2304) + (lrow & 31)*S64;
    #pragma unroll
    for (int jj = 0; jj < 2; ++jj) {
      short8 tv = *(const short8*)&trow[cq16 + 8*jj];
      short8 o2, o3;
      #pragma unroll
      for (int e = 0; e < 8; ++e) {
        const int j = cq16 + 8*jj + e;
        const float t = bf2f((unsigned short)tv[e]);
        o2[e] = (short)f2bf(-t * s_sbe[j] * s_swv[j]);
        o3[e] = (short)f2bf( t * s_sbe[j]);
      }
      *(short8*)&trow[cq16 + 8*jj]  = o2;   // T2
      *(short8*)&t3row[cq16 + 8*jj] = o3;   // T3
    }
    #pragma unroll
    for (int j = 0; j < 2; ++j) {
      f32x16 ckt = z16();
      #pragma unroll
      for (int kk = 0; kk < 2; ++kk) {
        const int kt = 2*w + kk;
        ckt = MM32(frg(a+AOF, SK, 32*j, kt, lane), ifrag(32*w, kt, lane), ckt);
      }
      stq(a+XS2, S64, 32*w, 32*j, lane, ckt);   // KT [128][72]
    }
  }
  BAR();

  // ---- ph8: W' (row-major!) -> AOF ; U (held in regs) ----
  f32x16 uacc[2];
  {
    #pragma unroll
    for (int j = 0; j < 2; ++j) {
      // C = KT . T2half^T = W'^T tile -> stq writes W' row-major [64 tok][SK]
      f32x16 cw = gemm32<4>(a+XS2, S64, 32*w, (j ? a+MRO : a+BOF+SLOT), S64, 0, z16(), lane);
      stq(a+AOF, SK, 32*j, 32*w, lane, cw);
      uacc[j] = gemm32<4>((j ? a+BOF+2304 : a+BOF), S64, 0, a+XS0, S64, 32*w, z16(), lane);
    }
  }
  BAR();

  // ---- ph9: W' copy-out (64 rows) ; KST copy ; U stq -> quarters ; wc ----
  {
    const int r2 = tid >> 2, seg = (tid & 3) * 32;
    #pragma unroll
    for (int j2 = 0; j2 < 4; ++j2) {
      short8 v8 = *(const short8*)&a[AOF + r2*SK + seg + 8*j2];
      *(short8*)(rec + WOFF + r2*128 + seg + 8*j2) = v8;
    }
    const int r = tid >> 1, half = (tid & 1) * 32;
    const float wc = s_swv[63];
    #pragma unroll
    for (int j2 = 0; j2 < 4; ++j2) {
      short8 kv = *(const short8*)&a[XS2 + r*S64 + half + 8*j2];
      short8 o;
      #pragma unroll
      for (int e = 0; e < 8; ++e) {
        const int tok = half + 8*j2 + e;
        o[e] = (short)f2bf(bf2f((unsigned short)kv[e]) * wc * s_swiv[tok]);
      }
      *(short8*)(rec + KOFF + r*64 + half + 8*j2) = o;
    }
    unsigned short* uq = a + ((w == 0) ? BOF : (w == 1) ? BOF+2304 : (w == 2) ? BOF+SLOT : MRO);
    stq(uq, S64, 0, 0, lane, uacc[0]);
    stq(uq, S64, 0, 32, lane, uacc[1]);
    if (tid == 0) wcs[hc] = wc;
  }
  BAR();

  // ---- ph10: U^T copy-out ----
  {
    const int r = tid >> 1, half = (tid & 1) * 32;
    const unsigned short* qb = a + ((r < 32) ? BOF : (r < 64) ? BOF+2304 : (r < 96) ? BOF+SLOT : MRO);
    #pragma unroll
    for (int j2 = 0; j2 < 4; ++j2) {
      short8 v8 = *(const short8*)&qb[(r & 31)*S64 + half + 8*j2];
      *(short8*)(rec + UOFF + r*64 + half + 8*j2) = v8;
    }
  }
}

// ================================ K2: sequential state scan ================================
#define SU   72
#define OW   0        // W'   [64][SK]
#define OK0  8704     // KST par0 [128][SU]
#define OK1  17920    // KST par1
#define OU   27136    // U^T half [64][SU]
#define OM0  31744    // M par0 [64][SU]
#define OM1  36352    // M par1
#define OS0T 40960    // S0^T [64][SK]
#define ODT  49664    // Delta^T [64][SU]

__global__ __launch_bounds__(512, 1)
void gdn_scan(const unsigned short* __restrict__ wsp, const float* __restrict__ wcs,
              float* __restrict__ Out, float* __restrict__ FS)
{
  __shared__ unsigned short a[54272];
  __shared__ float s_ob[64*68];

  const int tid = threadIdx.x, w = tid >> 6, lane = tid & 63;
  const int head = blockIdx.x % NH, vh = blockIdx.x / NH;   // pair (head,0),(head,1): same XCD
  const unsigned short* recs = wsp + (size_t)head * NCH * REC;
  float* op = Out + (size_t)head * SEQL * DD + vh * 64;

  const int mtS = w >> 1, ntS = w & 1;        // S-update tiles (8)
  const int mt4 = (w & 3) >> 1, nt4 = w & 1;  // per-half 4-tile map

  f32x16 s = z16(), oqr = z16();

  const int wr = tid >> 3, wc16 = (tid & 7) * 16;  // W rows 64
  const int kr = tid >> 2, kc16 = (tid & 3) * 16;  // KST rows 128
  const int ur = tid >> 3, uc8 = (tid & 7) * 8;    // U/M rows 64

  short8 stW0, stW1, stK0, stK1, stU, stM, qb[8];
  float wc_cur = 0.f, wcn = 0.f;

  auto issue = [&](int c){
    const unsigned short* rec = recs + (size_t)c * REC;
    stW0 = *(const short8*)(rec + WOFF + wr*128 + wc16);
    stW1 = *(const short8*)(rec + WOFF + wr*128 + wc16 + 8);
    stK0 = *(const short8*)(rec + KOFF + kr*64 + kc16);
    stK1 = *(const short8*)(rec + KOFF + kr*64 + kc16 + 8);
    stU  = *(const short8*)(rec + UOFF + (vh*64 + ur)*64 + uc8);
    stM  = *(const short8*)(rec + MOFF + ur*64 + uc8);
    if (w >= 4) {
      #pragma unroll
      for (int kt = 0; kt < 8; ++kt)
        qb[kt] = *(const short8*)(rec + QOFF + (32*nt4 + (lane & 31))*DD + kt*16 + ((lane >> 5) << 3));
    }
    wcn = wcs[head*NCH + c];
  };
  auto dswrite = [&](int par){
    *(short8*)&a[OW + wr*SK + wc16]     = stW0;
    *(short8*)&a[OW + wr*SK + wc16 + 8] = stW1;
    unsigned short* bk = a + (par ? OK1 : OK0);
    *(short8*)&bk[kr*SU + kc16]     = stK0;
    *(short8*)&bk[kr*SU + kc16 + 8] = stK1;
    *(short8*)&a[OU + ur*SU + uc8] = stU;
    unsigned short* bm = a + (par ? OM1 : OM0);
    *(short8*)&bm[ur*SU + uc8] = stM;
  };

  issue(0);
  wc_cur = wcn;
  dswrite(0);
  stq(a+OS0T, SK, 32*ntS, 32*mtS, lane, s);   // S0 = 0
  BAR();

  for (int c = 0; c < NCH; ++c) {
    const int cur = c & 1;

    // ---------------- PH1: Delta | Oq | out copy-out | issue next ----------------
    if (c > 0) {
      const int row = tid >> 3, c8 = (tid & 7) * 8;
      f32x4 v0 = *(const f32x4*)&s_ob[row*68 + c8];
      f32x4 v1 = *(const f32x4*)&s_ob[row*68 + c8 + 4];
      float* dst = op + (size_t)((c-1)*CC + row) * DD + c8;
      *(f32x4*)dst = v0;
      *(f32x4*)(dst + 4) = v1;
    }
    if (w < 4) {
      f32x16 d = gemm32<8>(a+OW, SK, 32*mt4, a+OS0T, SK, 32*nt4, z16(), lane);
      const int nn = 32*nt4 + (lane & 31), hh = (lane >> 5) << 2;
      #pragma unroll
      for (int q = 0; q < 4; ++q) {
        ushort4v u4 = *(const ushort4v*)&a[OU + nn*SU + 32*mt4 + 8*q + hh];
        ushort4v pt;
        #pragma unroll
        for (int si = 0; si < 4; ++si) pt[si] = f2bf(d[4*q+si] + bf2f(u4[si]));
        *(ushort4v*)&a[ODT + nn*SU + 32*mt4 + 8*q + hh] = pt;
      }
    } else {
      f32x16 o = z16();
      #pragma unroll
      for (int kt = 0; kt < 8; ++kt)
        o = MM32(frg(a+OS0T, SK, 32*mt4, kt, lane), qb[kt], o);
      oqr = o;
    }
    if (c < NCH-1) issue(c+1);
    BAR();

    // ---------------- PH2: S update | out | stage next ----------------
    {
      f32x16 sa;
      #pragma unroll
      for (int r = 0; r < 16; ++r) sa[r] = s[r] * wc_cur;
      s = gemm32<4>(a + (cur ? OK1 : OK0), SU, 32*mtS, a+ODT, SU, 32*ntS, sa, lane);
    }
    if (w >= 4) {
      f32x16 o = gemm32<4>(a+ODT, SU, 32*mt4, a + (cur ? OM1 : OM0), SU, 32*nt4, oqr, lane);
      stqf(s_ob, 68, 32*nt4, 32*mt4, lane, o);
    }
    stq(a+OS0T, SK, 32*ntS, 32*mtS, lane, s);
    if (c < NCH-1) { dswrite(cur ^ 1); wc_cur = wcn; }
    BAR();
  }

  // epilogue: last out tile + final state
  {
    const int row = tid >> 3, c8 = (tid & 7) * 8;
    f32x4 v0 = *(const f32x4*)&s_ob[row*68 + c8];
    f32x4 v1 = *(const f32x4*)&s_ob[row*68 + c8 + 4];
    float* dst = op + (size_t)((NCH-1)*CC + row) * DD + c8;
    *(f32x4*)dst = v0;
    *(f32x4*)(dst + 4) = v1;
  }
  {
    float* fsp = FS + (size_t)head * DD * DD + vh * 64;
    const int nn = 32*ntS + (lane & 31), hh = (lane >> 5) << 2;
    #pragma unroll
    for (int q = 0; q < 4; ++q)
      #pragma unroll
      for (int si = 0; si < 4; ++si)
        fsp[(size_t)(32*mtS + 8*q + hh + si) * DD + nn] = s[4*q + si];
  }
}

// ================================ fallback (R3, verified) ================================
__global__ __launch_bounds__(512, 1)
void gdn_chunk2(const float* __restrict__ Qg, const float* __restrict__ Kg,
                const float* __restrict__ Vg, const float* __restrict__ Gg,
                const float* __restrict__ Bg,
                float* __restrict__ Out, float* __restrict__ FS)
{
  __shared__ __align__(16) unsigned short sKc[64*SK];
  __shared__ __align__(16) unsigned short sQc[64*SK];
  __shared__ __align__(16) unsigned short sS0T[64*SK];
  __shared__ __align__(16) unsigned short sVc[64*S64];
  __shared__ __align__(16) unsigned short sVT[64*S64];
  __shared__ __align__(16) unsigned short sM[64*S64];
  __shared__ __align__(16) unsigned short sAr[8*SLOT];
  __shared__ float sbe2[2][64], swv2[2][64], swiv2[2][64];

  const int tid  = threadIdx.x;
  const int w    = tid >> 6;
  const int lane = tid & 63;
  const int half = w >> 2;
  const int j    = w & 3;
  const int mt   = j >> 1, nt = j & 1;
  const int mtS  = w >> 1, ntS = w & 1;
  const int mtK  = w >> 2, ntK = w & 3;
  const int head = blockIdx.x % NH;
  const int vh   = blockIdx.x / NH;

  const size_t rb = (size_t)head * SEQL * DD;
  const float* qp = Qg + rb;
  const float* kp = Kg + rb;
  const float* vp = Vg + rb + vh * 64;
  const float* gp = Gg + (size_t)head * SEQL;
  const float* bp = Bg + (size_t)head * SEQL;
  float* op  = Out + rb + vh * 64;
  float* fsp = FS + (size_t)head * DD * DD + vh * 64;

  const int lrow = tid >> 3;
  const int c16  = (tid & 7) * 16;
  const int c8   = (tid & 7) * 8;

  unsigned short* const sl0 = sAr + 0*SLOT;
  unsigned short* const sl1 = sAr + 1*SLOT;
  unsigned short* const sl2 = sAr + 2*SLOT;
  unsigned short* const sl3 = sAr + 3*SLOT;
  unsigned short* const sl4 = sAr + 4*SLOT;
  unsigned short* const sl5 = sAr + 5*SLOT;
  unsigned short* const sl6 = sAr + 6*SLOT;
  unsigned short* const sl7 = sAr + 7*SLOT;

  f32x16 s = z16(), oacc = z16();
  f32x4 kr[4], qr[4], vr[2]; float gr = 0.f, br = 0.f;

  auto prefetch = [&](int t0p){
    const float* kb = kp + (size_t)(t0p + lrow) * DD + c16;
    const float* qb = qp + (size_t)(t0p + lrow) * DD + c16;
    const float* vb = vp + (size_t)(t0p + lrow) * DD + c8;
    #pragma unroll
    for (int i = 0; i < 4; ++i) { kr[i] = *(const f32x4*)(kb + 4*i); qr[i] = *(const f32x4*)(qb + 4*i); }
    #pragma unroll
    for (int i = 0; i < 2; ++i) vr[i] = *(const f32x4*)(vb + 4*i);
    if (w == 7) { gr = gp[t0p + lane]; br = bp[t0p + lane]; }
  };
  auto scan_to = [&](int p){
    if (w == 7) {
      float sc = gr;
      #pragma unroll
      for (int d = 1; d < 64; d <<= 1) { float t = __shfl_up(sc, d); if (lane >= d) sc += t; }
      swv2[p][lane]  = __expf(sc);
      swiv2[p][lane] = __expf(-sc);
      sbe2[p][lane]  = br;
    }
  };

  prefetch(0);
  scan_to(0);
  BAR();

  for (int tc = 0; tc < NCH; ++tc) {
    const int t0 = tc * CC;
    const int cur = tc & 1, nxt = cur ^ 1;
    {
      float ssk = 0.f, ssq = 0.f;
      #pragma unroll
      for (int i = 0; i < 4; ++i) {
        ssk += kr[i][0]*kr[i][0] + kr[i][1]*kr[i][1] + kr[i][2]*kr[i][2] + kr[i][3]*kr[i][3];
        ssq += qr[i][0]*qr[i][0] + qr[i][1]*qr[i][1] + qr[i][2]*qr[i][2] + qr[i][3]*qr[i][3];
      }
      ssk += __shfl_xor(ssk, 1); ssk += __shfl_xor(ssk, 2); ssk += __shfl_xor(ssk, 4);
      ssq += __shfl_xor(ssq, 1); ssq += __shfl_xor(ssq, 2); ssq += __shfl_xor(ssq, 4);
      const float ik = 1.f / fmaxf(sqrtf(ssk), 1e-6f);
      const float iq = 0.08838834764831845f / fmaxf(sqrtf(ssq), 1e-6f) * swv2[cur][lrow];
      #pragma unroll
      for (int i = 0; i < 4; ++i) {
        ushort4v pk, pq;
        #pragma unroll
        for (int r = 0; r < 4; ++r) { pk[r] = f2bf(kr[i][r] * ik); pq[r] = f2bf(qr[i][r] * iq); }
        *(ushort4v*)&sKc[lrow*SK + c16 + 4*i] = pk;
        *(ushort4v*)&sQc[lrow*SK + c16 + 4*i] = pq;
      }
      #pragma unroll
      for (int i = 0; i < 2; ++i) {
        ushort4v pv;
        #pragma unroll
        for (int r = 0; r < 4; ++r) pv[r] = f2bf(vr[i][r]);
        *(ushort4v*)&sVc[lrow*S64 + c8 + 4*i] = pv;
      }
    }
    stq(sS0T, SK, 32*ntS, 32*mtS, lane, s);
    prefetch(tc < NCH-1 ? (tc+1)*CC : t0);
    BAR();

    if (half == 0) {
      f32x16 aa = gemm32<8>(sKc, SK, 32*mt, sKc, SK, 32*nt, z16(), lane);
      const int nn = 32*nt + (lane & 31), hh = (lane >> 5) << 2;
      #pragma unroll
      for (int q = 0; q < 4; ++q) {
        ushort4v pR, pL, pPT, pP;
        #pragma unroll
        for (int si = 0; si < 4; ++si) {
          const int r = 4*q + si, mm = 32*mt + 8*q + hh + si;
          const float S = aa[r];
          const float av  = (mm > nn) ? sbe2[cur][mm]*swv2[cur][mm]*swiv2[cur][nn]*S : 0.f;
          const float atr = (nn > mm) ? sbe2[cur][nn]*swv2[cur][nn]*swiv2[cur][mm]*S : 0.f;
          pR[si]  = f2bf(av);
          pL[si]  = f2bf(atr);
          pPT[si] = f2bf(((mm==nn)?1.f:0.f) - av);
          pP[si]  = f2bf(((mm==nn)?1.f:0.f) - atr);
        }
        const int off = nn*S64 + 32*mt + 8*q + hh;
        *(ushort4v*)&sl1[off] = pR;
        *(ushort4v*)&sl0[off] = pL;
        *(ushort4v*)&sl5[off] = pPT;
        *(ushort4v*)&sl4[off] = pP;
      }
    } else {
      f32x16 aa = gemm32<8>(sKc, SK, 32*mt, sQc, SK, 32*nt, z16(), lane);
      const int nn = 32*nt + (lane & 31), hh = (lane >> 5) << 2;
      #pragma unroll
      for (int q = 0; q < 4; ++q) {
        ushort4v pv;
        #pragma unroll
        for (int si = 0; si < 4; ++si) {
          const int r = 4*q + si, mm = 32*mt + 8*q + hh + si;
          pv[si] = f2bf((mm <= nn) ? aa[r]*swiv2[cur][mm] : 0.f);
        }
        *(ushort4v*)&sM[nn*S64 + 32*mt + 8*q + hh] = pv;
      }
    }
    BAR();

    if (half == 0) {
      f32x16 aa = gemm32<4>(sl0, S64, 32*mt, sl1, S64, 32*nt, z16(), lane);
      stq(sl3, S64, 32*nt, 32*mt, lane, aa);
      f32x16 bb = z16();
      #pragma unroll
      for (int kk = 0; kk < 2; ++kk) {
        const int kt = 2*nt + kk;
        bb = MM32(frg(sVc, S64, 32*mt, kt, lane), ifrag(32*nt, kt, lane), bb);
      }
      stq(sVT, S64, 32*nt, 32*mt, lane, bb);
    } else {
      f32x16 aa = gemm32<4>(sl1, S64, 32*mt, sl0, S64, 32*nt, z16(), lane);
      stq(sl2, S64, 32*nt, 32*mt, lane, aa);
      oacc = gemm32<8>(sQc, SK, 32*mt, sS0T, SK, 32*nt, z16(), lane);
    }
    BAR();

    {
      unsigned short* const inL[3]   = { sl2, sl0, sl2 };
      unsigned short* const inR[3]   = { sl3, sl1, sl3 };
      unsigned short* const outL[3]  = { sl0, sl2, sl0 };
      unsigned short* const outR[3]  = { sl1, sl3, sl1 };
      unsigned short* const inP[3]   = { sl4, sl7, sl5 };
      unsigned short* const inPT[3]  = { sl5, sl6, sl4 };
      unsigned short* const outP[3]  = { sl7, sl5, sl7 };
      unsigned short* const outPT[3] = { sl6, sl4, sl6 };
      #pragma unroll
      for (int lev = 0; lev < 3; ++lev) {
        if (half == 0) {
          f32x16 aa = gemm32<4>(inL[lev], S64, 32*mt, inR[lev], S64, 32*nt, z16(), lane);
          stq(outR[lev], S64, 32*nt, 32*mt, lane, aa);
          f32x16 p = ldq(inPT[lev], S64, 32*nt, 32*mt, lane);
          p = gemm32<4>(inP[lev], S64, 32*mt, inR[lev], S64, 32*nt, p, lane);
          stq(outPT[lev], S64, 32*nt, 32*mt, lane, p);
        } else {
          f32x16 aa = gemm32<4>(inR[lev], S64, 32*mt, inL[lev], S64, 32*nt, z16(), lane);
          stq(outL[lev], S64, 32*nt, 32*mt, lane, aa);
          f32x16 p = ldq(inP[lev], S64, 32*nt, 32*mt, lane);
          p = gemm32<4>(inR[lev], S64, 32*mt, inP[lev], S64, 32*nt, p, lane);
          stq(outP[lev], S64, 32*nt, 32*mt, lane, p);
        }
        BAR();
      }
    }

    if (half == 0) {
      f32x16 aa = gemm32<4>(sl0, S64, 32*mt, sl1, S64, 32*nt, z16(), lane);
      stq(sl2, S64, 32*nt, 32*mt, lane, aa);
    } else {
      f32x16 p = ldq(sl7, S64, 32*nt, 32*mt, lane);
      p = gemm32<4>(sl1, S64, 32*mt, sl7, S64, 32*nt, p, lane);
      stq(sl4, S64, 32*nt, 32*mt, lane, p);
    }
    BAR();

    if (half == 0) {
      f32x16 p = ldq(sl4, S64, 32*nt, 32*mt, lane);
      p = gemm32<4>(sl2, S64, 32*mt, sl4, S64, 32*nt, p, lane);
      const int nn = 32*nt + (lane & 31), hh = (lane >> 5) << 2;
      #pragma unroll
      for (int q = 0; q < 4; ++q) {
        ushort4v p2, p3;
        #pragma unroll
        for (int si = 0; si < 4; ++si) {
          const int r = 4*q + si, mm = 32*mt + 8*q + hh + si;
          const float t = p[r];
          p2[si] = f2bf(-t * sbe2[cur][mm] * swv2[cur][mm]);
          p3[si] = f2bf( t * sbe2[cur][mm]);
        }
        const int off = nn*S64 + 32*mt + 8*q + hh;
        *(ushort4v*)&sl1[off] = p2;
        *(ushort4v*)&sl5[off] = p3;
      }
    } else {
      f32x16 zz = gemm32<8>(sKc, SK, 32*mt, sS0T, SK, 32*nt, z16(), lane);
      stq(sl0, S64, 32*nt, 32*mt, lane, zz);
    }
    {
      f32x16 aa = z16();
      #pragma unroll
      for (int kk = 0; kk < 2; ++kk) {
        const int kt = 2*ntK + kk;
        aa = MM32(frg(sKc, SK, 32*mtK, kt, lane), ifrag(32*ntK, kt, lane), aa);
      }
      stq(sl6, S64, 32*ntK, 32*mtK, lane, aa);
    }
    BAR();

    if (half == 0) {
      f32x16 d = gemm32<4>(sl5, S64, 32*mt, sVT, S64, 32*nt, z16(), lane);
      d = gemm32<4>(sl1, S64, 32*mt, sl0, S64, 32*nt, d, lane);
      const int nn = 32*nt + (lane & 31), hh = (lane >> 5) << 2;
      const float w63 = swv2[cur][63];
      #pragma unroll
      for (int q = 0; q < 4; ++q) {
        ushort4v pt, ps;
        #pragma unroll
        for (int si = 0; si < 4; ++si) {
          const int r = 4*q + si, mm = 32*mt + 8*q + hh + si;
          pt[si] = f2bf(d[r]);
          ps[si] = f2bf(d[r] * w63 * swiv2[cur][mm]);
        }
        const int off = nn*S64 + 32*mt + 8*q + hh;
        *(ushort4v*)&sl3[off] = pt;
        *(ushort4v*)&sl2[off] = ps;
      }
    }
    scan_to(nxt);
    {
      const float w63 = swv2[cur][63];
      #pragma unroll
      for (int r = 0; r < 16; ++r) s[r] *= w63;
    }
    BAR();

    s = gemm32<4>(sl6, S64, 32*mtS, sl2, S64, 32*ntS, s, lane);
    if (half == 1) {
      f32x16 o = oacc;
      o = gemm32<4>(sM, S64, 32*mt, sl3, S64, 32*nt, o, lane);
      const int nn = 32*nt + (lane & 31), hh = (lane >> 5) << 2;
      #pragma unroll
      for (int q = 0; q < 4; ++q)
        #pragma unroll
        for (int si = 0; si < 4; ++si)
          op[(size_t)(t0 + 32*mt + 8*q + hh + si) * DD + nn] = o[4*q + si];
    }
    BAR();
  }

  {
    const int nn = 32*ntS + (lane & 31), hh = (lane >> 5) << 2;
    #pragma unroll
    for (int q = 0; q < 4; ++q)
      #pragma unroll
      for (int si = 0; si < 4; ++si)
        fsp[(size_t)(32*mtS + 8*q + hh + si) * DD + nn] = s[4*q + si];
  }
}

extern "C" void kernel_launch(void* const* d_in, const int* in_sizes, int n_in,
                              void* d_out, int out_size, void* d_ws, size_t ws_size,
                              hipStream_t stream) {
  const float* Q = (const float*)d_in[0];
  const float* K = (const float*)d_in[1];
  const float* V = (const float*)d_in[2];
  const float* G = (const float*)d_in[3];
  const float* B = (const float*)d_in[4];
  float* Out = (float*)d_out;
  float* FS  = Out + (size_t)NH * SEQL * DD;

  const size_t WS_NEED = (size_t)NH * NCH * REC * 2 + (size_t)NH * NCH * 4;
  if (ws_size >= WS_NEED) {
    unsigned short* wsp = (unsigned short*)d_ws;
    float* wcs = (float*)(wsp + (size_t)NH * NCH * REC);
    hipLaunchKernelGGL(gdn_prep, dim3(NH*NCH), dim3(256), 0, stream, Q, K, V, G, B, wsp, wcs);
    hipLaunchKernelGGL(gdn_scan, dim3(NH*2), dim3(512), 0, stream, wsp, wcs, Out, FS);
  } else {
    hipLaunchKernelGGL(gdn_chunk2, dim3(NH*2), dim3(512), 0, stream, Q, K, V, G, B, Out, FS);
  }
}